// Round 1
// baseline (1750.180 us; speedup 1.0000x reference)
//
#include <hip/hip_runtime.h>
#include <cstdint>
#include <cstddef>

// ---------------- problem constants ----------------
// B=16, L=128, E=256, H=256, RR=128, BIO=64, NT=3, V=30000, R=25

typedef __attribute__((ext_vector_type(8))) short short8;
typedef __attribute__((ext_vector_type(4))) float f32x4;

__device__ __forceinline__ unsigned short f2bf(float f) {
  unsigned int u = __float_as_uint(f);
  u += 0x7fffu + ((u >> 16) & 1u);
  return (unsigned short)(u >> 16);
}

// ---------------- init: zero accumulators ----------------
__global__ void k_init(float* acc) {
  if (threadIdx.x < 8) acc[threadIdx.x] = 0.f;
}

// ---------------- embedding gather ----------------
__global__ void k_embed(const int* __restrict__ tok, const float* __restrict__ wemb,
                        float* __restrict__ emb) {
  int bl = blockIdx.x;
  int t = threadIdx.x;
  int w = tok[bl];
  emb[bl * 256 + t] = wemb[(size_t)w * 256 + t];
}

// ---------------- pre-pack W_hh (1024x256 f32) into MFMA B-frag bf16 layout ----------------
// frag f = nt*8+kt; slot lane holds 8 bf16: row = nt*16+(lane&15), k = kt*32+(lane>>4)*8 + j
__global__ void k_prepack(const float* __restrict__ W, uint4* __restrict__ Wpk) {
  int idx = blockIdx.x * 256 + threadIdx.x; // 0..32767
  int lane = idx & 63;
  int kt = (idx >> 6) & 7;
  int nt = idx >> 9;
  int row = nt * 16 + (lane & 15);
  int k0 = kt * 32 + ((lane >> 4) << 3);
  union { unsigned short us[8]; uint4 v; } tmp;
#pragma unroll
  for (int j = 0; j < 8; ++j) tmp.us[j] = f2bf(W[(size_t)row * 256 + k0 + j]);
  Wpk[idx] = tmp.v;
}

// ---------------- generic fp32 GEMM: C[m,n] = act(sum_k A[m,k]*W[n,k] + bias[n]) ----------------
// A: MxK (row stride K), W: NxK rows (row stride ldw), C row stride N.
// BM=BN=64, BK=16, 256 threads, 4x4 per thread. M%64==0, N%64==0, K%16==0 assumed.
template <bool RELU, bool BIAS>
__global__ __launch_bounds__(256) void k_gemm(
    const float* __restrict__ A, const float* __restrict__ W,
    const float* __restrict__ bias, float* __restrict__ C,
    int M, int N, int K, int ldw) {
  __shared__ float As[16][68];
  __shared__ float Ws[16][68];
  int bn = blockIdx.x, bm = blockIdx.y;
  int tid = threadIdx.x;
  int tx = tid & 15, ty = tid >> 4;
  int lr = tid >> 2;
  int lc = (tid & 3) << 2;
  const float* Ap = A + (size_t)(bm * 64 + lr) * K + lc;
  const float* Wp = W + (size_t)(bn * 64 + lr) * ldw + lc;
  float acc[4][4] = {};
  for (int k0 = 0; k0 < K; k0 += 16) {
    float4 av = *reinterpret_cast<const float4*>(Ap + k0);
    float4 wv = *reinterpret_cast<const float4*>(Wp + k0);
    As[lc + 0][lr] = av.x; As[lc + 1][lr] = av.y; As[lc + 2][lr] = av.z; As[lc + 3][lr] = av.w;
    Ws[lc + 0][lr] = wv.x; Ws[lc + 1][lr] = wv.y; Ws[lc + 2][lr] = wv.z; Ws[lc + 3][lr] = wv.w;
    __syncthreads();
#pragma unroll
    for (int kk = 0; kk < 16; ++kk) {
      const float4 a4 = *reinterpret_cast<const float4*>(&As[kk][ty << 2]);
      const float4 w4 = *reinterpret_cast<const float4*>(&Ws[kk][tx << 2]);
      acc[0][0] += a4.x * w4.x; acc[0][1] += a4.x * w4.y; acc[0][2] += a4.x * w4.z; acc[0][3] += a4.x * w4.w;
      acc[1][0] += a4.y * w4.x; acc[1][1] += a4.y * w4.y; acc[1][2] += a4.y * w4.z; acc[1][3] += a4.y * w4.w;
      acc[2][0] += a4.z * w4.x; acc[2][1] += a4.z * w4.y; acc[2][2] += a4.z * w4.z; acc[2][3] += a4.z * w4.w;
      acc[3][0] += a4.w * w4.x; acc[3][1] += a4.w * w4.y; acc[3][2] += a4.w * w4.z; acc[3][3] += a4.w * w4.w;
    }
    __syncthreads();
  }
#pragma unroll
  for (int i = 0; i < 4; ++i) {
    int row = bm * 64 + (ty << 2) + i;
#pragma unroll
    for (int j2 = 0; j2 < 4; ++j2) {
      int col = bn * 64 + (tx << 2) + j2;
      float v = acc[i][j2];
      if (BIAS) v += bias[col];
      if (RELU) v = fmaxf(v, 0.f);
      C[(size_t)row * N + col] = v;
    }
  }
}

// ---------------- LSTM: one block per direction, 1024 threads (16 waves) ----------------
// Wave w owns gate rows j in [w*16, w*16+16): tiles {w (i), w+16 (f), w+32 (g), w+48 (o)}.
// h carried as bf16 in LDS; c carried in lane registers (lane owns (b=q*4+r, j=w*16+n)).
__global__ __launch_bounds__(1024) void k_lstm(
    const float* __restrict__ xg_f, const float* __restrict__ xg_b,
    const uint4* __restrict__ Wpk_f, const uint4* __restrict__ Wpk_b,
    float* __restrict__ hsf, float* __restrict__ hsb) {
  int dir = blockIdx.x;
  const float* xg = dir ? xg_b : xg_f;
  const uint4* Wpk = dir ? Wpk_b : Wpk_f;
  float* hseq = dir ? hsb : hsf;

  __shared__ __align__(16) unsigned short hsh[16][264]; // bf16 h, padded pitch

  int tid = threadIdx.x;
  int w = tid >> 6;
  int lane = tid & 63;
  int n = lane & 15;
  int q = lane >> 4;
  int j = (w << 4) + n;

  for (int idx = tid; idx < 16 * 264; idx += 1024) (&hsh[0][0])[idx] = 0;
  __syncthreads();

  float cst[4] = {0.f, 0.f, 0.f, 0.f};
  const uint4* hrow = reinterpret_cast<const uint4*>(&hsh[lane & 15][0]);

  for (int s = 0; s < 128; ++s) {
    int t = dir ? (127 - s) : s;
    // prefetch xg for this step (independent of h)
    float xv[4][4];
#pragma unroll
    for (int r = 0; r < 4; ++r) {
      int b = (q << 2) + r;
      const float* xb = xg + (size_t)((b << 7) + t) * 1024;
      xv[r][0] = xb[j];
      xv[r][1] = xb[256 + j];
      xv[r][2] = xb[512 + j];
      xv[r][3] = xb[768 + j];
    }
    // A-frags: lane m=lane&15 (batch), k = kt*32 + q*8 + jj
    short8 afr[8];
#pragma unroll
    for (int kt = 0; kt < 8; ++kt)
      afr[kt] = __builtin_bit_cast(short8, hrow[(kt << 2) + q]);
    __syncthreads(); // everyone has read old h

    f32x4 aI = {0.f, 0.f, 0.f, 0.f}, aF = {0.f, 0.f, 0.f, 0.f};
    f32x4 aG = {0.f, 0.f, 0.f, 0.f}, aO = {0.f, 0.f, 0.f, 0.f};
#pragma unroll
    for (int kt = 0; kt < 8; ++kt) {
      uint4 b0 = Wpk[(((w) << 3) + kt) * 64 + lane];
      uint4 b1 = Wpk[(((w + 16) << 3) + kt) * 64 + lane];
      uint4 b2 = Wpk[(((w + 32) << 3) + kt) * 64 + lane];
      uint4 b3 = Wpk[(((w + 48) << 3) + kt) * 64 + lane];
      aI = __builtin_amdgcn_mfma_f32_16x16x32_bf16(afr[kt], __builtin_bit_cast(short8, b0), aI, 0, 0, 0);
      aF = __builtin_amdgcn_mfma_f32_16x16x32_bf16(afr[kt], __builtin_bit_cast(short8, b1), aF, 0, 0, 0);
      aG = __builtin_amdgcn_mfma_f32_16x16x32_bf16(afr[kt], __builtin_bit_cast(short8, b2), aG, 0, 0, 0);
      aO = __builtin_amdgcn_mfma_f32_16x16x32_bf16(afr[kt], __builtin_bit_cast(short8, b3), aO, 0, 0, 0);
    }

#pragma unroll
    for (int r = 0; r < 4; ++r) {
      int b = (q << 2) + r;
      float gi = aI[r] + xv[r][0];
      float gf = aF[r] + xv[r][1];
      float gg = aG[r] + xv[r][2];
      float go = aO[r] + xv[r][3];
      gi = fminf(fmaxf(gi, -30.f), 30.f);
      gf = fminf(fmaxf(gf, -30.f), 30.f);
      gg = fminf(fmaxf(gg, -30.f), 30.f);
      go = fminf(fmaxf(go, -30.f), 30.f);
      float si = __fdividef(1.f, 1.f + __expf(-gi));
      float sf = __fdividef(1.f, 1.f + __expf(-gf));
      float so = __fdividef(1.f, 1.f + __expf(-go));
      float eg = __expf(-2.f * gg);
      float tg = __fdividef(1.f - eg, 1.f + eg);
      float c = sf * cst[r] + si * tg;
      cst[r] = c;
      float cc = fminf(fmaxf(c, -30.f), 30.f);
      float ec = __expf(-2.f * cc);
      float th = __fdividef(1.f - ec, 1.f + ec);
      float h = so * th;
      hseq[(size_t)((b << 7) + t) * 256 + j] = h;
      hsh[b][j] = f2bf(h);
    }
    __syncthreads(); // new h visible
  }
}

// ---------------- o = 0.5*(hf+hb); oc = concat(o, bio_emb[bio]) ----------------
__global__ void k_oc(const float* __restrict__ hf, const float* __restrict__ hb,
                     const int* __restrict__ bio, const float* __restrict__ bioE,
                     float* __restrict__ o, float* __restrict__ oc) {
  int bl = blockIdx.x;
  int t = threadIdx.x; // 320
  if (t < 256) {
    float v = 0.5f * (hf[bl * 256 + t] + hb[bl * 256 + t]);
    o[bl * 256 + t] = v;
    oc[bl * 320 + t] = v;
  } else {
    oc[bl * 320 + t] = bioE[bio[bl] * 64 + (t - 256)];
  }
}

// ---------------- emi = o @ emi_W^T + emi_b  (N=3) ----------------
__global__ void k_emi(const float* __restrict__ o, const float* __restrict__ emiW,
                      const float* __restrict__ emib, float* __restrict__ emi) {
  int bl = blockIdx.x;
  int t = threadIdx.x; // 64
  float p0 = 0.f, p1 = 0.f, p2 = 0.f;
  for (int k = t; k < 256; k += 64) {
    float ov = o[bl * 256 + k];
    p0 += ov * emiW[k];
    p1 += ov * emiW[256 + k];
    p2 += ov * emiW[512 + k];
  }
#pragma unroll
  for (int off = 32; off; off >>= 1) {
    p0 += __shfl_down(p0, off);
    p1 += __shfl_down(p1, off);
    p2 += __shfl_down(p2, off);
  }
  if (t == 0) {
    emi[bl * 3 + 0] = p0 + emib[0];
    emi[bl * 3 + 1] = p1 + emib[1];
    emi[bl * 3 + 2] = p2 + emib[2];
  }
}

// ---------------- fused selection loss ----------------
// block = (b, i-pair); threads: tid<128 -> i0, else i1; j = tid&127
__global__ __launch_bounds__(256) void k_sel(
    const float* __restrict__ abuf, const float* __restrict__ cbuf,
    const float* __restrict__ suvb, const float* __restrict__ rel,
    const float* __restrict__ y, const int* __restrict__ tok,
    float* __restrict__ acc) {
  __shared__ unsigned short alds[128][136]; // a[b][j][h] as bf16, [h][j] layout
  __shared__ float cbs[2][128];
  __shared__ float red[4];
  int blk = blockIdx.x;
  int b = blk >> 6;
  int ip = blk & 63;
  int tid = threadIdx.x;
  int hh = tid & 127;
  int half = tid >> 7;
  for (int j2 = half; j2 < 128; j2 += 2)
    alds[hh][j2] = f2bf(abuf[(size_t)((b << 7) + j2) * 128 + hh]);
  {
    int i = (ip << 1) + half;
    cbs[half][hh] = cbuf[(size_t)((b << 7) + i) * 128 + hh] + suvb[hh];
  }
  __syncthreads();
  int i = (ip << 1) + half;
  int j = hh;
  float lg[25];
#pragma unroll
  for (int r = 0; r < 25; ++r) lg[r] = 0.f;
  for (int h = 0; h < 128; ++h) {
    float av = __uint_as_float(((unsigned int)alds[h][j]) << 16);
    float uv = fmaxf(av + cbs[half][h], 0.f);
#pragma unroll
    for (int r = 0; r < 25; ++r) lg[r] += uv * rel[r * 128 + h]; // rel: wave-uniform -> scalar loads
  }
  float mi = (tok[(b << 7) + i] != 0) ? 1.f : 0.f;
  float mj = (tok[(b << 7) + j] != 0) ? 1.f : 0.f;
  const float* yp = y + (size_t)((b << 7) + i) * 3200 + j;
  float bs = 0.f;
#pragma unroll
  for (int r = 0; r < 25; ++r) {
    float x = lg[r];
    float yv = yp[r * 128];
    bs += fmaxf(x, 0.f) - x * yv + log1pf(__expf(-fabsf(x)));
  }
  bs *= mi * mj;
#pragma unroll
  for (int off = 32; off; off >>= 1) bs += __shfl_down(bs, off);
  if ((tid & 63) == 0) red[tid >> 6] = bs;
  __syncthreads();
  if (tid == 0) atomicAdd(&acc[0], red[0] + red[1] + red[2] + red[3]);
}

// ---------------- CRF loss (num & den) per batch ----------------
__global__ __launch_bounds__(128) void k_crf(
    const float* __restrict__ emi, const int* __restrict__ bio, const int* __restrict__ tok,
    const float* __restrict__ cstart, const float* __restrict__ cend,
    const float* __restrict__ ctrans, float* __restrict__ acc) {
  int b = blockIdx.x;
  int t = threadIdx.x;
  __shared__ float elds[128][4];
  __shared__ float msk[128];
  __shared__ int biol[128];
  __shared__ float r_t[2], r_m[2];
  biol[t] = bio[b * 128 + t];
  msk[t] = (tok[b * 128 + t] != 0) ? 1.f : 0.f;
#pragma unroll
  for (int g = 0; g < 3; ++g) elds[t][g] = emi[(b * 128 + t) * 3 + g];
  __syncthreads();
  float m = msk[t];
  float term;
  if (t == 0)
    term = cstart[biol[0]] + elds[0][biol[0]];
  else
    term = (ctrans[biol[t - 1] * 3 + biol[t]] + elds[t][biol[t]]) * m;
  float ms = m;
#pragma unroll
  for (int off = 32; off; off >>= 1) {
    term += __shfl_down(term, off);
    ms += __shfl_down(ms, off);
  }
  if ((t & 63) == 0) { r_t[t >> 6] = term; r_m[t >> 6] = ms; }
  __syncthreads();
  if (t == 0) {
    float num = r_t[0] + r_t[1];
    float msum = r_m[0] + r_m[1];
    int se = (int)msum - 1;
    if (se < 0) se = 0;
    num += cend[biol[se]];
    float tr[9];
#pragma unroll
    for (int i2 = 0; i2 < 9; ++i2) tr[i2] = ctrans[i2];
    float s0 = cstart[0] + elds[0][0];
    float s1 = cstart[1] + elds[0][1];
    float s2 = cstart[2] + elds[0][2];
    for (int tt = 1; tt < 128; ++tt) {
      float a0, a1, a2, mx, n0, n1, n2;
      a0 = s0 + tr[0]; a1 = s1 + tr[3]; a2 = s2 + tr[6];
      mx = fmaxf(a0, fmaxf(a1, a2));
      n0 = mx + __logf(__expf(a0 - mx) + __expf(a1 - mx) + __expf(a2 - mx)) + elds[tt][0];
      a0 = s0 + tr[1]; a1 = s1 + tr[4]; a2 = s2 + tr[7];
      mx = fmaxf(a0, fmaxf(a1, a2));
      n1 = mx + __logf(__expf(a0 - mx) + __expf(a1 - mx) + __expf(a2 - mx)) + elds[tt][1];
      a0 = s0 + tr[2]; a1 = s1 + tr[5]; a2 = s2 + tr[8];
      mx = fmaxf(a0, fmaxf(a1, a2));
      n2 = mx + __logf(__expf(a0 - mx) + __expf(a1 - mx) + __expf(a2 - mx)) + elds[tt][2];
      if (msk[tt] != 0.f) { s0 = n0; s1 = n1; s2 = n2; }
    }
    float a0 = s0 + cend[0], a1 = s1 + cend[1], a2 = s2 + cend[2];
    float mx = fmaxf(a0, fmaxf(a1, a2));
    float den = mx + __logf(__expf(a0 - mx) + __expf(a1 - mx) + __expf(a2 - mx));
    atomicAdd(&acc[1], num - den);
    atomicAdd(&acc[2], msum);
  }
}

// ---------------- finalize ----------------
__global__ void k_fin(const float* __restrict__ acc, float* __restrict__ out) {
  if (threadIdx.x == 0 && blockIdx.x == 0)
    out[0] = -(acc[1] * (1.f / 16.f)) + acc[0] / acc[2];
}

// ---------------- host launcher ----------------
extern "C" void kernel_launch(void* const* d_in, const int* in_sizes, int n_in,
                              void* d_out, int out_size, void* d_ws, size_t ws_size,
                              hipStream_t stream) {
  const int* tokens = (const int*)d_in[0];
  const int* bio = (const int*)d_in[1];
  const float* selg = (const float*)d_in[2];
  const float* wemb = (const float*)d_in[3];
  const float* Wihf = (const float*)d_in[4];
  const float* Whhf = (const float*)d_in[5];
  const float* bf = (const float*)d_in[6];
  const float* Wihb = (const float*)d_in[7];
  const float* Whhb = (const float*)d_in[8];
  const float* bb = (const float*)d_in[9];
  const float* emiW = (const float*)d_in[10];
  const float* emib = (const float*)d_in[11];
  const float* bioE = (const float*)d_in[12];
  const float* suW = (const float*)d_in[13];
  const float* sub = (const float*)d_in[14];
  const float* svW = (const float*)d_in[15];
  const float* svb = (const float*)d_in[16];
  const float* suvW = (const float*)d_in[17];
  const float* suvb = (const float*)d_in[18];
  const float* rel = (const float*)d_in[19];
  const float* cstart = (const float*)d_in[20];
  const float* cend = (const float*)d_in[21];
  const float* ctrans = (const float*)d_in[22];

  float* ws = (float*)d_ws;
  float* emb = ws;                         // 524288
  float* xgf = emb + 524288;               // 2097152
  float* xgb = xgf + 2097152;              // 2097152
  float* hf = xgb + 2097152;               // 524288
  float* hb = hf + 524288;                 // 524288
  float* o = hb + 524288;                  // 524288
  float* oc = o + 524288;                  // 655360
  float* u = oc + 655360;                  // 262144
  float* v = u + 262144;                   // 262144
  float* abuf = v + 262144;                // 262144
  float* cbuf = abuf + 262144;             // 262144
  float* emi = cbuf + 262144;              // 6144
  float* wpkf = emi + 6144;                // 131072 floats (bf16 packed)
  float* wpkb = wpkf + 131072;             // 131072
  float* acc = wpkb + 131072;              // 8

  k_init<<<1, 64, 0, stream>>>(acc);
  k_embed<<<2048, 256, 0, stream>>>(tokens, wemb, emb);
  k_prepack<<<128, 256, 0, stream>>>(Whhf, (uint4*)wpkf);
  k_prepack<<<128, 256, 0, stream>>>(Whhb, (uint4*)wpkb);
  k_gemm<false, true><<<dim3(16, 32), 256, 0, stream>>>(emb, Wihf, bf, xgf, 2048, 1024, 256, 256);
  k_gemm<false, true><<<dim3(16, 32), 256, 0, stream>>>(emb, Wihb, bb, xgb, 2048, 1024, 256, 256);
  k_lstm<<<2, 1024, 0, stream>>>(xgf, xgb, (const uint4*)wpkf, (const uint4*)wpkb, hf, hb);
  k_oc<<<2048, 320, 0, stream>>>(hf, hb, bio, bioE, o, oc);
  k_emi<<<2048, 64, 0, stream>>>(o, emiW, emib, emi);
  k_gemm<true, true><<<dim3(2, 32), 256, 0, stream>>>(oc, suW, sub, u, 2048, 128, 320, 320);
  k_gemm<true, true><<<dim3(2, 32), 256, 0, stream>>>(oc, svW, svb, v, 2048, 128, 320, 320);
  k_gemm<false, false><<<dim3(2, 32), 256, 0, stream>>>(u, suvW, nullptr, abuf, 2048, 128, 128, 256);
  k_gemm<false, false><<<dim3(2, 32), 256, 0, stream>>>(v, suvW + 128, nullptr, cbuf, 2048, 128, 128, 256);
  k_sel<<<1024, 256, 0, stream>>>(abuf, cbuf, suvb, rel, selg, tokens, acc);
  k_crf<<<16, 128, 0, stream>>>(emi, bio, tokens, cstart, cend, ctrans, acc);
  k_fin<<<1, 64, 0, stream>>>(acc, (float*)d_out);
}

// Round 2
// 1080.299 us; speedup vs baseline: 1.6201x; 1.6201x over previous
//
#include <hip/hip_runtime.h>
#include <cstdint>
#include <cstddef>

// ---------------- problem constants ----------------
// B=16, L=128, E=256, H=256, RR=128, BIO=64, NT=3, V=30000, R=25

typedef __attribute__((ext_vector_type(8))) short short8;
typedef __attribute__((ext_vector_type(4))) float f32x4;

__device__ __forceinline__ unsigned short f2bf(float f) {
  unsigned int u = __float_as_uint(f);
  u += 0x7fffu + ((u >> 16) & 1u);
  return (unsigned short)(u >> 16);
}

// ---------------- init: zero accumulators + sync flags ----------------
__global__ void k_init(float* acc) {
  if (threadIdx.x < 16) acc[threadIdx.x] = 0.f;
}

// ---------------- embedding gather ----------------
__global__ void k_embed(const int* __restrict__ tok, const float* __restrict__ wemb,
                        float* __restrict__ emb) {
  int bl = blockIdx.x;
  int t = threadIdx.x;
  int w = tok[bl];
  emb[bl * 256 + t] = wemb[(size_t)w * 256 + t];
}

// ---------------- pre-pack W_hh (1024x256 f32) into MFMA B-frag bf16 layout ----------------
// frag f = nt*8+kt; lane holds 8 bf16: row = nt*16+(lane&15), k = kt*32+(lane>>4)*8 + j
__global__ void k_prepack(const float* __restrict__ W, uint4* __restrict__ Wpk) {
  int idx = blockIdx.x * 256 + threadIdx.x; // 0..32767
  int lane = idx & 63;
  int kt = (idx >> 6) & 7;
  int nt = idx >> 9;
  int row = nt * 16 + (lane & 15);
  int k0 = kt * 32 + ((lane >> 4) << 3);
  union { unsigned short us[8]; uint4 v; } tmp;
#pragma unroll
  for (int j = 0; j < 8; ++j) tmp.us[j] = f2bf(W[(size_t)row * 256 + k0 + j]);
  Wpk[idx] = tmp.v;
}

// ---------------- generic fp32 GEMM: C[m,n] = act(sum_k A[m,k]*W[n,k] + bias[n]) ----------------
template <bool RELU, bool BIAS>
__global__ __launch_bounds__(256) void k_gemm(
    const float* __restrict__ A, const float* __restrict__ W,
    const float* __restrict__ bias, float* __restrict__ C,
    int M, int N, int K, int ldw) {
  __shared__ float As[16][68];
  __shared__ float Ws[16][68];
  int bn = blockIdx.x, bm = blockIdx.y;
  int tid = threadIdx.x;
  int tx = tid & 15, ty = tid >> 4;
  int lr = tid >> 2;
  int lc = (tid & 3) << 2;
  const float* Ap = A + (size_t)(bm * 64 + lr) * K + lc;
  const float* Wp = W + (size_t)(bn * 64 + lr) * ldw + lc;
  float acc[4][4] = {};
  for (int k0 = 0; k0 < K; k0 += 16) {
    float4 av = *reinterpret_cast<const float4*>(Ap + k0);
    float4 wv = *reinterpret_cast<const float4*>(Wp + k0);
    As[lc + 0][lr] = av.x; As[lc + 1][lr] = av.y; As[lc + 2][lr] = av.z; As[lc + 3][lr] = av.w;
    Ws[lc + 0][lr] = wv.x; Ws[lc + 1][lr] = wv.y; Ws[lc + 2][lr] = wv.z; Ws[lc + 3][lr] = wv.w;
    __syncthreads();
#pragma unroll
    for (int kk = 0; kk < 16; ++kk) {
      const float4 a4 = *reinterpret_cast<const float4*>(&As[kk][ty << 2]);
      const float4 w4 = *reinterpret_cast<const float4*>(&Ws[kk][tx << 2]);
      acc[0][0] += a4.x * w4.x; acc[0][1] += a4.x * w4.y; acc[0][2] += a4.x * w4.z; acc[0][3] += a4.x * w4.w;
      acc[1][0] += a4.y * w4.x; acc[1][1] += a4.y * w4.y; acc[1][2] += a4.y * w4.z; acc[1][3] += a4.y * w4.w;
      acc[2][0] += a4.z * w4.x; acc[2][1] += a4.z * w4.y; acc[2][2] += a4.z * w4.z; acc[2][3] += a4.z * w4.w;
      acc[3][0] += a4.w * w4.x; acc[3][1] += a4.w * w4.y; acc[3][2] += a4.w * w4.z; acc[3][3] += a4.w * w4.w;
    }
    __syncthreads();
  }
#pragma unroll
  for (int i = 0; i < 4; ++i) {
    int row = bm * 64 + (ty << 2) + i;
#pragma unroll
    for (int j2 = 0; j2 < 4; ++j2) {
      int col = bn * 64 + (tx << 2) + j2;
      float v = acc[i][j2];
      if (BIAS) v += bias[col];
      if (RELU) v = fmaxf(v, 0.f);
      C[(size_t)row * N + col] = v;
    }
  }
}

// ---------------- LSTM v2: 4 blocks = (2 dirs) x (2 j-halves), 512 threads ----------------
// All of this block's W_hh quarter (256 KB bf16) lives in VGPRs (128/lane).
// Wave w owns hidden j in [p*128 + w*16, +16) -> gate row-tiles nt = gate*16 + p*8 + w.
// h (bf16, 16 batches x 256) double-buffered in LDS; halves exchanged per step
// via global hx buffer + monotonic agent-scope flag handshake (parity double-buffered).
__global__ __launch_bounds__(512, 2) void k_lstm2(
    const float* __restrict__ xg_f, const float* __restrict__ xg_b,
    const uint4* __restrict__ Wpk_f, const uint4* __restrict__ Wpk_b,
    float* __restrict__ hsf, float* __restrict__ hsb,
    unsigned int* __restrict__ flags, unsigned long long* __restrict__ hxq) {
  int dir = blockIdx.x >> 1;
  int p = blockIdx.x & 1;
  const float* xg = dir ? xg_b : xg_f;
  const uint4* Wpk = dir ? Wpk_b : Wpk_f;
  float* hseq = dir ? hsb : hsf;

  __shared__ __align__(16) unsigned short hshA[16][264];
  __shared__ __align__(16) unsigned short hshB[16][264];

  int tid = threadIdx.x;
  int w = tid >> 6;          // wave 0..7
  int lane = tid & 63;
  int n = lane & 15;
  int q = lane >> 4;         // 0..3
  int jl = p * 128 + w * 16 + n;  // this lane's hidden index (for its 4 h outputs)

  // ---- load persistent B-frags: 4 gates x 8 kt = 32 uint4 = 128 VGPRs/lane ----
  uint4 bfr[4][8];
#pragma unroll
  for (int g = 0; g < 4; ++g) {
    int nt = g * 16 + p * 8 + w;
#pragma unroll
    for (int kt = 0; kt < 8; ++kt)
      bfr[g][kt] = Wpk[(nt * 8 + kt) * 64 + lane];
  }

  for (int idx = tid; idx < 16 * 264; idx += 512) {
    (&hshA[0][0])[idx] = 0;
    (&hshB[0][0])[idx] = 0;
  }
  __syncthreads();

  float cst[4] = {0.f, 0.f, 0.f, 0.f};
  unsigned int* myflag = &flags[dir * 2 + p];
  unsigned int* pflag = &flags[dir * 2 + (1 - p)];

  for (int s = 0; s < 128; ++s) {
    int t = dir ? (127 - s) : s;
    unsigned short(*cur)[264] = (s & 1) ? hshB : hshA;
    unsigned short(*nxt)[264] = (s & 1) ? hshA : hshB;

    // xg gate biases for this step (independent of h -> issue early)
    float xv[4][4];
#pragma unroll
    for (int r = 0; r < 4; ++r) {
      int b = (q << 2) + r;
      const float* xb = xg + (size_t)((b << 7) + t) * 1024;
      xv[r][0] = xb[jl];
      xv[r][1] = xb[256 + jl];
      xv[r][2] = xb[512 + jl];
      xv[r][3] = xb[768 + jl];
    }

    // A-frags from LDS: lane m = lane&15 (batch), k = kt*32 + q*8 .. +8
    const uint4* hrow = reinterpret_cast<const uint4*>(&cur[n][0]);
    short8 afr[8];
#pragma unroll
    for (int kt = 0; kt < 8; ++kt)
      afr[kt] = __builtin_bit_cast(short8, hrow[(kt << 2) + q]);

    f32x4 aI = {0.f, 0.f, 0.f, 0.f}, aF = {0.f, 0.f, 0.f, 0.f};
    f32x4 aG = {0.f, 0.f, 0.f, 0.f}, aO = {0.f, 0.f, 0.f, 0.f};
#pragma unroll
    for (int kt = 0; kt < 8; ++kt) {
      aI = __builtin_amdgcn_mfma_f32_16x16x32_bf16(afr[kt], __builtin_bit_cast(short8, bfr[0][kt]), aI, 0, 0, 0);
      aF = __builtin_amdgcn_mfma_f32_16x16x32_bf16(afr[kt], __builtin_bit_cast(short8, bfr[1][kt]), aF, 0, 0, 0);
      aG = __builtin_amdgcn_mfma_f32_16x16x32_bf16(afr[kt], __builtin_bit_cast(short8, bfr[2][kt]), aG, 0, 0, 0);
      aO = __builtin_amdgcn_mfma_f32_16x16x32_bf16(afr[kt], __builtin_bit_cast(short8, bfr[3][kt]), aO, 0, 0, 0);
    }

    // nonlinearity: lane owns (b = q*4+r, j = jl)
    unsigned short h4[4];
#pragma unroll
    for (int r = 0; r < 4; ++r) {
      int b = (q << 2) + r;
      float gi = aI[r] + xv[r][0];
      float gf = aF[r] + xv[r][1];
      float gg = aG[r] + xv[r][2];
      float go = aO[r] + xv[r][3];
      gi = fminf(fmaxf(gi, -30.f), 30.f);
      gf = fminf(fmaxf(gf, -30.f), 30.f);
      gg = fminf(fmaxf(gg, -30.f), 30.f);
      go = fminf(fmaxf(go, -30.f), 30.f);
      float si = __fdividef(1.f, 1.f + __expf(-gi));
      float sf = __fdividef(1.f, 1.f + __expf(-gf));
      float so = __fdividef(1.f, 1.f + __expf(-go));
      float eg = __expf(-2.f * gg);
      float tg = __fdividef(1.f - eg, 1.f + eg);
      float c = sf * cst[r] + si * tg;
      cst[r] = c;
      float cc = fminf(fmaxf(c, -30.f), 30.f);
      float ec = __expf(-2.f * cc);
      float th = __fdividef(1.f - ec, 1.f + ec);
      float h = so * th;
      hseq[(size_t)((b << 7) + t) * 256 + jl] = h;
      unsigned short hb16 = f2bf(h);
      h4[r] = hb16;
      nxt[b][jl] = hb16;  // own half of next-h in LDS
    }

    if (s < 127) {
      int par = s & 1;
      // export own half: hx2 layout [region][jl_local][b], 8B per lane
      unsigned long long hv = (unsigned long long)h4[0] |
                              ((unsigned long long)h4[1] << 16) |
                              ((unsigned long long)h4[2] << 32) |
                              ((unsigned long long)h4[3] << 48);
      int jll = w * 16 + n;  // 0..127 within own half
      int reg_own = ((dir * 2 + par) * 2 + p);
      hxq[reg_own * 512 + jll * 4 + q] = hv;
      __threadfence();
      __syncthreads();  // all lanes' hx stores drained (vmcnt0) + fenced
      if (tid == 0) {
        __hip_atomic_fetch_add(myflag, 1u, __ATOMIC_RELEASE, __HIP_MEMORY_SCOPE_AGENT);
        while (__hip_atomic_load(pflag, __ATOMIC_ACQUIRE, __HIP_MEMORY_SCOPE_AGENT) < (unsigned)(s + 1)) {
          __builtin_amdgcn_s_sleep(1);
        }
      }
      __syncthreads();  // partner data globally visible
      // import partner half (agent-scope loads bypass L1 -> always fresh)
      int reg_par = ((dir * 2 + par) * 2 + (1 - p));
      unsigned long long v = __hip_atomic_load(&hxq[reg_par * 512 + tid],
                                               __ATOMIC_RELAXED, __HIP_MEMORY_SCOPE_AGENT);
      int jp = (1 - p) * 128 + (tid >> 2);
      int b0 = (tid & 3) << 2;
      nxt[b0 + 0][jp] = (unsigned short)(v);
      nxt[b0 + 1][jp] = (unsigned short)(v >> 16);
      nxt[b0 + 2][jp] = (unsigned short)(v >> 32);
      nxt[b0 + 3][jp] = (unsigned short)(v >> 48);
      __syncthreads();  // nxt complete before next iteration reads it
    }
  }
}

// ---------------- o = 0.5*(hf+hb); oc = concat(o, bio_emb[bio]) ----------------
__global__ void k_oc(const float* __restrict__ hf, const float* __restrict__ hb,
                     const int* __restrict__ bio, const float* __restrict__ bioE,
                     float* __restrict__ o, float* __restrict__ oc) {
  int bl = blockIdx.x;
  int t = threadIdx.x; // 320
  if (t < 256) {
    float v = 0.5f * (hf[bl * 256 + t] + hb[bl * 256 + t]);
    o[bl * 256 + t] = v;
    oc[bl * 320 + t] = v;
  } else {
    oc[bl * 320 + t] = bioE[bio[bl] * 64 + (t - 256)];
  }
}

// ---------------- emi = o @ emi_W^T + emi_b  (N=3) ----------------
__global__ void k_emi(const float* __restrict__ o, const float* __restrict__ emiW,
                      const float* __restrict__ emib, float* __restrict__ emi) {
  int bl = blockIdx.x;
  int t = threadIdx.x; // 64
  float p0 = 0.f, p1 = 0.f, p2 = 0.f;
  for (int k = t; k < 256; k += 64) {
    float ov = o[bl * 256 + k];
    p0 += ov * emiW[k];
    p1 += ov * emiW[256 + k];
    p2 += ov * emiW[512 + k];
  }
#pragma unroll
  for (int off = 32; off; off >>= 1) {
    p0 += __shfl_down(p0, off);
    p1 += __shfl_down(p1, off);
    p2 += __shfl_down(p2, off);
  }
  if (t == 0) {
    emi[bl * 3 + 0] = p0 + emib[0];
    emi[bl * 3 + 1] = p1 + emib[1];
    emi[bl * 3 + 2] = p2 + emib[2];
  }
}

// ---------------- fused selection loss ----------------
__global__ __launch_bounds__(256) void k_sel(
    const float* __restrict__ abuf, const float* __restrict__ cbuf,
    const float* __restrict__ suvb, const float* __restrict__ rel,
    const float* __restrict__ y, const int* __restrict__ tok,
    float* __restrict__ acc) {
  __shared__ unsigned short alds[128][136];
  __shared__ float cbs[2][128];
  __shared__ float red[4];
  int blk = blockIdx.x;
  int b = blk >> 6;
  int ip = blk & 63;
  int tid = threadIdx.x;
  int hh = tid & 127;
  int half = tid >> 7;
  for (int j2 = half; j2 < 128; j2 += 2)
    alds[hh][j2] = f2bf(abuf[(size_t)((b << 7) + j2) * 128 + hh]);
  {
    int i = (ip << 1) + half;
    cbs[half][hh] = cbuf[(size_t)((b << 7) + i) * 128 + hh] + suvb[hh];
  }
  __syncthreads();
  int i = (ip << 1) + half;
  int j = hh;
  float lg[25];
#pragma unroll
  for (int r = 0; r < 25; ++r) lg[r] = 0.f;
  for (int h = 0; h < 128; ++h) {
    float av = __uint_as_float(((unsigned int)alds[h][j]) << 16);
    float uv = fmaxf(av + cbs[half][h], 0.f);
#pragma unroll
    for (int r = 0; r < 25; ++r) lg[r] += uv * rel[r * 128 + h];
  }
  float mi = (tok[(b << 7) + i] != 0) ? 1.f : 0.f;
  float mj = (tok[(b << 7) + j] != 0) ? 1.f : 0.f;
  const float* yp = y + (size_t)((b << 7) + i) * 3200 + j;
  float bs = 0.f;
#pragma unroll
  for (int r = 0; r < 25; ++r) {
    float x = lg[r];
    float yv = yp[r * 128];
    bs += fmaxf(x, 0.f) - x * yv + log1pf(__expf(-fabsf(x)));
  }
  bs *= mi * mj;
#pragma unroll
  for (int off = 32; off; off >>= 1) bs += __shfl_down(bs, off);
  if ((tid & 63) == 0) red[tid >> 6] = bs;
  __syncthreads();
  if (tid == 0) atomicAdd(&acc[0], red[0] + red[1] + red[2] + red[3]);
}

// ---------------- CRF loss (num & den) per batch ----------------
__global__ __launch_bounds__(128) void k_crf(
    const float* __restrict__ emi, const int* __restrict__ bio, const int* __restrict__ tok,
    const float* __restrict__ cstart, const float* __restrict__ cend,
    const float* __restrict__ ctrans, float* __restrict__ acc) {
  int b = blockIdx.x;
  int t = threadIdx.x;
  __shared__ float elds[128][4];
  __shared__ float msk[128];
  __shared__ int biol[128];
  __shared__ float r_t[2], r_m[2];
  biol[t] = bio[b * 128 + t];
  msk[t] = (tok[b * 128 + t] != 0) ? 1.f : 0.f;
#pragma unroll
  for (int g = 0; g < 3; ++g) elds[t][g] = emi[(b * 128 + t) * 3 + g];
  __syncthreads();
  float m = msk[t];
  float term;
  if (t == 0)
    term = cstart[biol[0]] + elds[0][biol[0]];
  else
    term = (ctrans[biol[t - 1] * 3 + biol[t]] + elds[t][biol[t]]) * m;
  float ms = m;
#pragma unroll
  for (int off = 32; off; off >>= 1) {
    term += __shfl_down(term, off);
    ms += __shfl_down(ms, off);
  }
  if ((t & 63) == 0) { r_t[t >> 6] = term; r_m[t >> 6] = ms; }
  __syncthreads();
  if (t == 0) {
    float num = r_t[0] + r_t[1];
    float msum = r_m[0] + r_m[1];
    int se = (int)msum - 1;
    if (se < 0) se = 0;
    num += cend[biol[se]];
    float tr[9];
#pragma unroll
    for (int i2 = 0; i2 < 9; ++i2) tr[i2] = ctrans[i2];
    float s0 = cstart[0] + elds[0][0];
    float s1 = cstart[1] + elds[0][1];
    float s2 = cstart[2] + elds[0][2];
    for (int tt = 1; tt < 128; ++tt) {
      float a0, a1, a2, mx, n0, n1, n2;
      a0 = s0 + tr[0]; a1 = s1 + tr[3]; a2 = s2 + tr[6];
      mx = fmaxf(a0, fmaxf(a1, a2));
      n0 = mx + __logf(__expf(a0 - mx) + __expf(a1 - mx) + __expf(a2 - mx)) + elds[tt][0];
      a0 = s0 + tr[1]; a1 = s1 + tr[4]; a2 = s2 + tr[7];
      mx = fmaxf(a0, fmaxf(a1, a2));
      n1 = mx + __logf(__expf(a0 - mx) + __expf(a1 - mx) + __expf(a2 - mx)) + elds[tt][1];
      a0 = s0 + tr[2]; a1 = s1 + tr[5]; a2 = s2 + tr[8];
      mx = fmaxf(a0, fmaxf(a1, a2));
      n2 = mx + __logf(__expf(a0 - mx) + __expf(a1 - mx) + __expf(a2 - mx)) + elds[tt][2];
      if (msk[tt] != 0.f) { s0 = n0; s1 = n1; s2 = n2; }
    }
    float a0 = s0 + cend[0], a1 = s1 + cend[1], a2 = s2 + cend[2];
    float mx = fmaxf(a0, fmaxf(a1, a2));
    float den = mx + __logf(__expf(a0 - mx) + __expf(a1 - mx) + __expf(a2 - mx));
    atomicAdd(&acc[1], num - den);
    atomicAdd(&acc[2], msum);
  }
}

// ---------------- finalize ----------------
__global__ void k_fin(const float* __restrict__ acc, float* __restrict__ out) {
  if (threadIdx.x == 0 && blockIdx.x == 0)
    out[0] = -(acc[1] * (1.f / 16.f)) + acc[0] / acc[2];
}

// ---------------- host launcher ----------------
extern "C" void kernel_launch(void* const* d_in, const int* in_sizes, int n_in,
                              void* d_out, int out_size, void* d_ws, size_t ws_size,
                              hipStream_t stream) {
  const int* tokens = (const int*)d_in[0];
  const int* bio = (const int*)d_in[1];
  const float* selg = (const float*)d_in[2];
  const float* wemb = (const float*)d_in[3];
  const float* Wihf = (const float*)d_in[4];
  const float* Whhf = (const float*)d_in[5];
  const float* bf = (const float*)d_in[6];
  const float* Wihb = (const float*)d_in[7];
  const float* Whhb = (const float*)d_in[8];
  const float* bb = (const float*)d_in[9];
  const float* emiW = (const float*)d_in[10];
  const float* emib = (const float*)d_in[11];
  const float* bioE = (const float*)d_in[12];
  const float* suW = (const float*)d_in[13];
  const float* sub = (const float*)d_in[14];
  const float* svW = (const float*)d_in[15];
  const float* svb = (const float*)d_in[16];
  const float* suvW = (const float*)d_in[17];
  const float* suvb = (const float*)d_in[18];
  const float* rel = (const float*)d_in[19];
  const float* cstart = (const float*)d_in[20];
  const float* cend = (const float*)d_in[21];
  const float* ctrans = (const float*)d_in[22];

  float* ws = (float*)d_ws;
  float* emb = ws;                         // 524288
  float* xgf = emb + 524288;               // 2097152
  float* xgb = xgf + 2097152;              // 2097152
  float* hf = xgb + 2097152;               // 524288
  float* hb = hf + 524288;                 // 524288
  float* o = hb + 524288;                  // 524288
  float* oc = o + 524288;                  // 655360
  float* u = oc + 655360;                  // 262144
  float* v = u + 262144;                   // 262144
  float* abuf = v + 262144;                // 262144
  float* cbuf = abuf + 262144;             // 262144
  float* emi = cbuf + 262144;              // 6144
  float* wpkf = emi + 6144;                // 131072 floats (bf16 packed)
  float* wpkb = wpkf + 131072;             // 131072
  float* acc = wpkb + 131072;              // 16 (acc[0..2] sums, [8..11] flags)
  unsigned int* flags = (unsigned int*)(acc + 8);
  unsigned long long* hxq = (unsigned long long*)(acc + 16); // 32 KB h-exchange

  k_init<<<1, 64, 0, stream>>>(acc);
  k_embed<<<2048, 256, 0, stream>>>(tokens, wemb, emb);
  k_prepack<<<128, 256, 0, stream>>>(Whhf, (uint4*)wpkf);
  k_prepack<<<128, 256, 0, stream>>>(Whhb, (uint4*)wpkb);
  k_gemm<false, true><<<dim3(16, 32), 256, 0, stream>>>(emb, Wihf, bf, xgf, 2048, 1024, 256, 256);
  k_gemm<false, true><<<dim3(16, 32), 256, 0, stream>>>(emb, Wihb, bb, xgb, 2048, 1024, 256, 256);
  k_lstm2<<<4, 512, 0, stream>>>(xgf, xgb, (const uint4*)wpkf, (const uint4*)wpkb, hf, hb, flags, hxq);
  k_oc<<<2048, 320, 0, stream>>>(hf, hb, bio, bioE, o, oc);
  k_emi<<<2048, 64, 0, stream>>>(o, emiW, emib, emi);
  k_gemm<true, true><<<dim3(2, 32), 256, 0, stream>>>(oc, suW, sub, u, 2048, 128, 320, 320);
  k_gemm<true, true><<<dim3(2, 32), 256, 0, stream>>>(oc, svW, svb, v, 2048, 128, 320, 320);
  k_gemm<false, false><<<dim3(2, 32), 256, 0, stream>>>(u, suvW, nullptr, abuf, 2048, 128, 128, 256);
  k_gemm<false, false><<<dim3(2, 32), 256, 0, stream>>>(v, suvW + 128, nullptr, cbuf, 2048, 128, 128, 256);
  k_sel<<<1024, 256, 0, stream>>>(abuf, cbuf, suvb, rel, selg, tokens, acc);
  k_crf<<<16, 128, 0, stream>>>(emi, bio, tokens, cstart, cend, ctrans, acc);
  k_fin<<<1, 64, 0, stream>>>(acc, (float*)d_out);
}

// Round 3
// 811.664 us; speedup vs baseline: 2.1563x; 1.3310x over previous
//
#include <hip/hip_runtime.h>
#include <cstdint>
#include <cstddef>

// ---------------- problem constants ----------------
// B=16, L=128, E=256, H=256, RR=128, BIO=64, NT=3, V=30000, R=25

typedef __attribute__((ext_vector_type(4))) float f32x4;

__device__ __forceinline__ unsigned short f2bf(float f) {
  unsigned int u = __float_as_uint(f);
  u += 0x7fffu + ((u >> 16) & 1u);
  return (unsigned short)(u >> 16);
}
__device__ __forceinline__ float bf2f(unsigned short u) {
  return __uint_as_float(((unsigned int)u) << 16);
}

// ---------------- init: zero accumulators ----------------
__global__ void k_init(float* acc) {
  if (threadIdx.x < 16) acc[threadIdx.x] = 0.f;
}

// ---------------- embedding gather ----------------
__global__ void k_embed(const int* __restrict__ tok, const float* __restrict__ wemb,
                        float* __restrict__ emb) {
  int bl = blockIdx.x;
  int t = threadIdx.x;
  int w = tok[bl];
  emb[bl * 256 + t] = wemb[(size_t)w * 256 + t];
}

// ---------------- pre-pack W_hh (1024x256 f32) into fp8 MFMA B-frag layout ----------------
// frag f = nt*8+kt; lane holds 8 fp8 bytes: row = nt*16+(lane&15), k = kt*32+(lane>>4)*8 + j
__global__ void k_prepack8(const float* __restrict__ W, uint2* __restrict__ Wpk) {
  int idx = blockIdx.x * 256 + threadIdx.x; // 0..32767
  int lane = idx & 63;
  int kt = (idx >> 6) & 7;
  int nt = idx >> 9;
  int row = nt * 16 + (lane & 15);
  int k0 = kt * 32 + ((lane >> 4) << 3);
  const float* wp = &W[(size_t)row * 256 + k0];
  int lo = 0, hi = 0;
  lo = __builtin_amdgcn_cvt_pk_fp8_f32(wp[0], wp[1], lo, false);
  lo = __builtin_amdgcn_cvt_pk_fp8_f32(wp[2], wp[3], lo, true);
  hi = __builtin_amdgcn_cvt_pk_fp8_f32(wp[4], wp[5], hi, false);
  hi = __builtin_amdgcn_cvt_pk_fp8_f32(wp[6], wp[7], hi, true);
  uint2 r;
  r.x = (unsigned)lo;
  r.y = (unsigned)hi;
  Wpk[idx] = r;
}

// ---------------- generic fp32 GEMM: C[m,n] = act(sum_k A[m,k]*W[n,k] + bias[n]) ----------------
// OUT16: store bf16 (ushort) instead of f32.
template <bool RELU, bool BIAS, bool OUT16>
__global__ __launch_bounds__(256) void k_gemm(
    const float* __restrict__ A, const float* __restrict__ W,
    const float* __restrict__ bias, void* __restrict__ Cv,
    int M, int N, int K, int ldw) {
  __shared__ float As[16][68];
  __shared__ float Ws[16][68];
  int bn = blockIdx.x, bm = blockIdx.y;
  int tid = threadIdx.x;
  int tx = tid & 15, ty = tid >> 4;
  int lr = tid >> 2;
  int lc = (tid & 3) << 2;
  const float* Ap = A + (size_t)(bm * 64 + lr) * K + lc;
  const float* Wp = W + (size_t)(bn * 64 + lr) * ldw + lc;
  float acc[4][4] = {};
  for (int k0 = 0; k0 < K; k0 += 16) {
    float4 av = *reinterpret_cast<const float4*>(Ap + k0);
    float4 wv = *reinterpret_cast<const float4*>(Wp + k0);
    As[lc + 0][lr] = av.x; As[lc + 1][lr] = av.y; As[lc + 2][lr] = av.z; As[lc + 3][lr] = av.w;
    Ws[lc + 0][lr] = wv.x; Ws[lc + 1][lr] = wv.y; Ws[lc + 2][lr] = wv.z; Ws[lc + 3][lr] = wv.w;
    __syncthreads();
#pragma unroll
    for (int kk = 0; kk < 16; ++kk) {
      const float4 a4 = *reinterpret_cast<const float4*>(&As[kk][ty << 2]);
      const float4 w4 = *reinterpret_cast<const float4*>(&Ws[kk][tx << 2]);
      acc[0][0] += a4.x * w4.x; acc[0][1] += a4.x * w4.y; acc[0][2] += a4.x * w4.z; acc[0][3] += a4.x * w4.w;
      acc[1][0] += a4.y * w4.x; acc[1][1] += a4.y * w4.y; acc[1][2] += a4.y * w4.z; acc[1][3] += a4.y * w4.w;
      acc[2][0] += a4.z * w4.x; acc[2][1] += a4.z * w4.y; acc[2][2] += a4.z * w4.z; acc[2][3] += a4.z * w4.w;
      acc[3][0] += a4.w * w4.x; acc[3][1] += a4.w * w4.y; acc[3][2] += a4.w * w4.z; acc[3][3] += a4.w * w4.w;
    }
    __syncthreads();
  }
#pragma unroll
  for (int i = 0; i < 4; ++i) {
    int row = bm * 64 + (ty << 2) + i;
#pragma unroll
    for (int j2 = 0; j2 < 4; ++j2) {
      int col = bn * 64 + (tx << 2) + j2;
      float v = acc[i][j2];
      if (BIAS) v += bias[col];
      if (RELU) v = fmaxf(v, 0.f);
      if (OUT16)
        ((unsigned short*)Cv)[(size_t)row * N + col] = f2bf(v);
      else
        ((float*)Cv)[(size_t)row * N + col] = v;
    }
  }
}

// ---------------- LSTM v3: ONE block per direction, 1024 threads, fp8 weights in VGPRs ----------------
// Wave w (0..15) owns hidden j in [w*16, w*16+16): gate tiles nt = g*16 + w, g=0..3.
// Full W_hh (fp8, 256 KB) resident in VGPRs: 4 gates x 8 kt = 32 uint2 = 64 VGPR/lane.
// h carried as fp8 in LDS (double-buffered). xg pre-activations read as bf16.
// No inter-block communication at all.
__global__ __launch_bounds__(1024) void k_lstm3(
    const unsigned short* __restrict__ xg_f, const unsigned short* __restrict__ xg_b,
    const uint2* __restrict__ Wpk_f, const uint2* __restrict__ Wpk_b,
    float* __restrict__ hsf, float* __restrict__ hsb) {
  int dir = blockIdx.x;
  const unsigned short* xg = dir ? xg_b : xg_f;
  const uint2* Wpk = dir ? Wpk_b : Wpk_f;
  float* hseq = dir ? hsb : hsf;

  __shared__ __align__(8) unsigned char hA[16][264]; // fp8 h, padded pitch (264 = 8*33)
  __shared__ __align__(8) unsigned char hB[16][264];

  int tid = threadIdx.x;
  int w = tid >> 6;   // wave 0..15
  int lane = tid & 63;
  int n = lane & 15;
  int q = lane >> 4;  // 0..3
  int jl = (w << 4) + n;

  // persistent fp8 B-frags: 64 VGPR/lane
  uint2 bfr[4][8];
#pragma unroll
  for (int g = 0; g < 4; ++g) {
#pragma unroll
    for (int kt = 0; kt < 8; ++kt)
      bfr[g][kt] = Wpk[((g * 16 + w) * 8 + kt) * 64 + lane];
  }

  for (int idx = tid; idx < 16 * 264; idx += 1024) {
    (&hA[0][0])[idx] = 0;
    (&hB[0][0])[idx] = 0;
  }
  __syncthreads();

  float cst[4] = {0.f, 0.f, 0.f, 0.f};

  for (int s = 0; s < 128; ++s) {
    int t = dir ? (127 - s) : s;
    const unsigned char(*cur)[264] = (s & 1) ? hB : hA;
    unsigned char(*nxt)[264] = (s & 1) ? hA : hB;

    // xg bf16 loads for this step (independent of h; issued before MFMA to hide)
    unsigned short xv[4][4];
#pragma unroll
    for (int r = 0; r < 4; ++r) {
      int b = (q << 2) + r;
      const unsigned short* xb = xg + (size_t)((b << 7) + t) * 1024 + jl;
      xv[r][0] = xb[0];
      xv[r][1] = xb[256];
      xv[r][2] = xb[512];
      xv[r][3] = xb[768];
    }

    // MFMA: A-frag m = lane&15 (batch), k = kt*32 + q*8 .. +8 (8 consecutive fp8 bytes)
    const uint2* hrow = reinterpret_cast<const uint2*>(&cur[n][0]);
    f32x4 ac0 = {0.f, 0.f, 0.f, 0.f}, ac1 = {0.f, 0.f, 0.f, 0.f};
    f32x4 ac2 = {0.f, 0.f, 0.f, 0.f}, ac3 = {0.f, 0.f, 0.f, 0.f};
#pragma unroll
    for (int kt = 0; kt < 8; ++kt) {
      long av = __builtin_bit_cast(long, hrow[(kt << 2) + q]);
      ac0 = __builtin_amdgcn_mfma_f32_16x16x32_fp8_fp8(av, __builtin_bit_cast(long, bfr[0][kt]), ac0, 0, 0, 0);
      ac1 = __builtin_amdgcn_mfma_f32_16x16x32_fp8_fp8(av, __builtin_bit_cast(long, bfr[1][kt]), ac1, 0, 0, 0);
      ac2 = __builtin_amdgcn_mfma_f32_16x16x32_fp8_fp8(av, __builtin_bit_cast(long, bfr[2][kt]), ac2, 0, 0, 0);
      ac3 = __builtin_amdgcn_mfma_f32_16x16x32_fp8_fp8(av, __builtin_bit_cast(long, bfr[3][kt]), ac3, 0, 0, 0);
    }

    // nonlinearity: lane owns (b = q*4+r, j = jl)
#pragma unroll
    for (int r = 0; r < 4; ++r) {
      int b = (q << 2) + r;
      float gi = ac0[r] + bf2f(xv[r][0]);
      float gf = ac1[r] + bf2f(xv[r][1]);
      float gg = ac2[r] + bf2f(xv[r][2]);
      float go = ac3[r] + bf2f(xv[r][3]);
      gi = fminf(fmaxf(gi, -30.f), 30.f);
      gf = fminf(fmaxf(gf, -30.f), 30.f);
      gg = fminf(fmaxf(gg, -30.f), 30.f);
      go = fminf(fmaxf(go, -30.f), 30.f);
      float si = __fdividef(1.f, 1.f + __expf(-gi));
      float sf = __fdividef(1.f, 1.f + __expf(-gf));
      float so = __fdividef(1.f, 1.f + __expf(-go));
      float eg = __expf(-2.f * gg);
      float tg = __fdividef(1.f - eg, 1.f + eg);
      float c = sf * cst[r] + si * tg;
      cst[r] = c;
      float cc = fminf(fmaxf(c, -30.f), 30.f);
      float ec = __expf(-2.f * cc);
      float th = __fdividef(1.f - ec, 1.f + ec);
      float h = so * th;
      hseq[(size_t)((b << 7) + t) * 256 + jl] = h;
      int pk = __builtin_amdgcn_cvt_pk_fp8_f32(h, h, 0, false);
      nxt[b][jl] = (unsigned char)(pk & 0xff);
    }
    __syncthreads(); // nxt complete; cur reads done
  }
}

// ---------------- o = 0.5*(hf+hb); oc = concat(o, bio_emb[bio]) ----------------
__global__ void k_oc(const float* __restrict__ hf, const float* __restrict__ hb,
                     const int* __restrict__ bio, const float* __restrict__ bioE,
                     float* __restrict__ o, float* __restrict__ oc) {
  int bl = blockIdx.x;
  int t = threadIdx.x; // 320
  if (t < 256) {
    float v = 0.5f * (hf[bl * 256 + t] + hb[bl * 256 + t]);
    o[bl * 256 + t] = v;
    oc[bl * 320 + t] = v;
  } else {
    oc[bl * 320 + t] = bioE[bio[bl] * 64 + (t - 256)];
  }
}

// ---------------- emi = o @ emi_W^T + emi_b  (N=3) ----------------
__global__ void k_emi(const float* __restrict__ o, const float* __restrict__ emiW,
                      const float* __restrict__ emib, float* __restrict__ emi) {
  int bl = blockIdx.x;
  int t = threadIdx.x; // 64
  float p0 = 0.f, p1 = 0.f, p2 = 0.f;
  for (int k = t; k < 256; k += 64) {
    float ov = o[bl * 256 + k];
    p0 += ov * emiW[k];
    p1 += ov * emiW[256 + k];
    p2 += ov * emiW[512 + k];
  }
#pragma unroll
  for (int off = 32; off; off >>= 1) {
    p0 += __shfl_down(p0, off);
    p1 += __shfl_down(p1, off);
    p2 += __shfl_down(p2, off);
  }
  if (t == 0) {
    emi[bl * 3 + 0] = p0 + emib[0];
    emi[bl * 3 + 1] = p1 + emib[1];
    emi[bl * 3 + 2] = p2 + emib[2];
  }
}

// ---------------- fused selection loss ----------------
__global__ __launch_bounds__(256) void k_sel(
    const float* __restrict__ abuf, const float* __restrict__ cbuf,
    const float* __restrict__ suvb, const float* __restrict__ rel,
    const float* __restrict__ y, const int* __restrict__ tok,
    float* __restrict__ acc) {
  __shared__ unsigned short alds[128][136];
  __shared__ float cbs[2][128];
  __shared__ float red[4];
  int blk = blockIdx.x;
  int b = blk >> 6;
  int ip = blk & 63;
  int tid = threadIdx.x;
  int hh = tid & 127;
  int half = tid >> 7;
  for (int j2 = half; j2 < 128; j2 += 2)
    alds[hh][j2] = f2bf(abuf[(size_t)((b << 7) + j2) * 128 + hh]);
  {
    int i = (ip << 1) + half;
    cbs[half][hh] = cbuf[(size_t)((b << 7) + i) * 128 + hh] + suvb[hh];
  }
  __syncthreads();
  int i = (ip << 1) + half;
  int j = hh;
  float lg[25];
#pragma unroll
  for (int r = 0; r < 25; ++r) lg[r] = 0.f;
  for (int h = 0; h < 128; ++h) {
    float av = __uint_as_float(((unsigned int)alds[h][j]) << 16);
    float uv = fmaxf(av + cbs[half][h], 0.f);
#pragma unroll
    for (int r = 0; r < 25; ++r) lg[r] += uv * rel[r * 128 + h];
  }
  float mi = (tok[(b << 7) + i] != 0) ? 1.f : 0.f;
  float mj = (tok[(b << 7) + j] != 0) ? 1.f : 0.f;
  const float* yp = y + (size_t)((b << 7) + i) * 3200 + j;
  float bs = 0.f;
#pragma unroll
  for (int r = 0; r < 25; ++r) {
    float x = lg[r];
    float yv = yp[r * 128];
    bs += fmaxf(x, 0.f) - x * yv + log1pf(__expf(-fabsf(x)));
  }
  bs *= mi * mj;
#pragma unroll
  for (int off = 32; off; off >>= 1) bs += __shfl_down(bs, off);
  if ((tid & 63) == 0) red[tid >> 6] = bs;
  __syncthreads();
  if (tid == 0) atomicAdd(&acc[0], red[0] + red[1] + red[2] + red[3]);
}

// ---------------- CRF loss (num & den) per batch ----------------
__global__ __launch_bounds__(128) void k_crf(
    const float* __restrict__ emi, const int* __restrict__ bio, const int* __restrict__ tok,
    const float* __restrict__ cstart, const float* __restrict__ cend,
    const float* __restrict__ ctrans, float* __restrict__ acc) {
  int b = blockIdx.x;
  int t = threadIdx.x;
  __shared__ float elds[128][4];
  __shared__ float msk[128];
  __shared__ int biol[128];
  __shared__ float r_t[2], r_m[2];
  biol[t] = bio[b * 128 + t];
  msk[t] = (tok[b * 128 + t] != 0) ? 1.f : 0.f;
#pragma unroll
  for (int g = 0; g < 3; ++g) elds[t][g] = emi[(b * 128 + t) * 3 + g];
  __syncthreads();
  float m = msk[t];
  float term;
  if (t == 0)
    term = cstart[biol[0]] + elds[0][biol[0]];
  else
    term = (ctrans[biol[t - 1] * 3 + biol[t]] + elds[t][biol[t]]) * m;
  float ms = m;
#pragma unroll
  for (int off = 32; off; off >>= 1) {
    term += __shfl_down(term, off);
    ms += __shfl_down(ms, off);
  }
  if ((t & 63) == 0) { r_t[t >> 6] = term; r_m[t >> 6] = ms; }
  __syncthreads();
  if (t == 0) {
    float num = r_t[0] + r_t[1];
    float msum = r_m[0] + r_m[1];
    int se = (int)msum - 1;
    if (se < 0) se = 0;
    num += cend[biol[se]];
    float tr[9];
#pragma unroll
    for (int i2 = 0; i2 < 9; ++i2) tr[i2] = ctrans[i2];
    float s0 = cstart[0] + elds[0][0];
    float s1 = cstart[1] + elds[0][1];
    float s2 = cstart[2] + elds[0][2];
    for (int tt = 1; tt < 128; ++tt) {
      float a0, a1, a2, mx, n0, n1, n2;
      a0 = s0 + tr[0]; a1 = s1 + tr[3]; a2 = s2 + tr[6];
      mx = fmaxf(a0, fmaxf(a1, a2));
      n0 = mx + __logf(__expf(a0 - mx) + __expf(a1 - mx) + __expf(a2 - mx)) + elds[tt][0];
      a0 = s0 + tr[1]; a1 = s1 + tr[4]; a2 = s2 + tr[7];
      mx = fmaxf(a0, fmaxf(a1, a2));
      n1 = mx + __logf(__expf(a0 - mx) + __expf(a1 - mx) + __expf(a2 - mx)) + elds[tt][1];
      a0 = s0 + tr[2]; a1 = s1 + tr[5]; a2 = s2 + tr[8];
      mx = fmaxf(a0, fmaxf(a1, a2));
      n2 = mx + __logf(__expf(a0 - mx) + __expf(a1 - mx) + __expf(a2 - mx)) + elds[tt][2];
      if (msk[tt] != 0.f) { s0 = n0; s1 = n1; s2 = n2; }
    }
    float a0 = s0 + cend[0], a1 = s1 + cend[1], a2 = s2 + cend[2];
    float mx = fmaxf(a0, fmaxf(a1, a2));
    float den = mx + __logf(__expf(a0 - mx) + __expf(a1 - mx) + __expf(a2 - mx));
    atomicAdd(&acc[1], num - den);
    atomicAdd(&acc[2], msum);
  }
}

// ---------------- finalize ----------------
__global__ void k_fin(const float* __restrict__ acc, float* __restrict__ out) {
  if (threadIdx.x == 0 && blockIdx.x == 0)
    out[0] = -(acc[1] * (1.f / 16.f)) + acc[0] / acc[2];
}

// ---------------- host launcher ----------------
extern "C" void kernel_launch(void* const* d_in, const int* in_sizes, int n_in,
                              void* d_out, int out_size, void* d_ws, size_t ws_size,
                              hipStream_t stream) {
  const int* tokens = (const int*)d_in[0];
  const int* bio = (const int*)d_in[1];
  const float* selg = (const float*)d_in[2];
  const float* wemb = (const float*)d_in[3];
  const float* Wihf = (const float*)d_in[4];
  const float* Whhf = (const float*)d_in[5];
  const float* bf = (const float*)d_in[6];
  const float* Wihb = (const float*)d_in[7];
  const float* Whhb = (const float*)d_in[8];
  const float* bb = (const float*)d_in[9];
  const float* emiW = (const float*)d_in[10];
  const float* emib = (const float*)d_in[11];
  const float* bioE = (const float*)d_in[12];
  const float* suW = (const float*)d_in[13];
  const float* sub = (const float*)d_in[14];
  const float* svW = (const float*)d_in[15];
  const float* svb = (const float*)d_in[16];
  const float* suvW = (const float*)d_in[17];
  const float* suvb = (const float*)d_in[18];
  const float* rel = (const float*)d_in[19];
  const float* cstart = (const float*)d_in[20];
  const float* cend = (const float*)d_in[21];
  const float* ctrans = (const float*)d_in[22];

  float* ws = (float*)d_ws;
  float* emb = ws;                          // 524288 f
  float* xgf16 = emb + 524288;              // 2097152 ushort = 1048576 f
  float* xgb16 = xgf16 + 1048576;           // 1048576 f
  float* hf = xgb16 + 1048576;              // 524288
  float* hb = hf + 524288;                  // 524288
  float* o = hb + 524288;                   // 524288
  float* oc = o + 524288;                   // 655360
  float* u = oc + 655360;                   // 262144
  float* v = u + 262144;                    // 262144
  float* abuf = v + 262144;                 // 262144
  float* cbuf = abuf + 262144;              // 262144
  float* emi = cbuf + 262144;               // 6144
  float* wpk8f = emi + 6144;                // 65536 f (256 KB fp8 packed)
  float* wpk8b = wpk8f + 65536;             // 65536 f
  float* acc = wpk8b + 65536;               // 16

  k_init<<<1, 64, 0, stream>>>(acc);
  k_embed<<<2048, 256, 0, stream>>>(tokens, wemb, emb);
  k_prepack8<<<128, 256, 0, stream>>>(Whhf, (uint2*)wpk8f);
  k_prepack8<<<128, 256, 0, stream>>>(Whhb, (uint2*)wpk8b);
  k_gemm<false, true, true><<<dim3(16, 32), 256, 0, stream>>>(emb, Wihf, bf, xgf16, 2048, 1024, 256, 256);
  k_gemm<false, true, true><<<dim3(16, 32), 256, 0, stream>>>(emb, Wihb, bb, xgb16, 2048, 1024, 256, 256);
  k_lstm3<<<2, 1024, 0, stream>>>((const unsigned short*)xgf16, (const unsigned short*)xgb16,
                                  (const uint2*)wpk8f, (const uint2*)wpk8b, hf, hb);
  k_oc<<<2048, 320, 0, stream>>>(hf, hb, bio, bioE, o, oc);
  k_emi<<<2048, 64, 0, stream>>>(o, emiW, emib, emi);
  k_gemm<true, true, false><<<dim3(2, 32), 256, 0, stream>>>(oc, suW, sub, u, 2048, 128, 320, 320);
  k_gemm<true, true, false><<<dim3(2, 32), 256, 0, stream>>>(oc, svW, svb, v, 2048, 128, 320, 320);
  k_gemm<false, false, false><<<dim3(2, 32), 256, 0, stream>>>(u, suvW, nullptr, abuf, 2048, 128, 128, 256);
  k_gemm<false, false, false><<<dim3(2, 32), 256, 0, stream>>>(v, suvW + 128, nullptr, cbuf, 2048, 128, 128, 256);
  k_sel<<<1024, 256, 0, stream>>>(abuf, cbuf, suvb, rel, selg, tokens, acc);
  k_crf<<<16, 128, 0, stream>>>(emi, bio, tokens, cstart, cend, ctrans, acc);
  k_fin<<<1, 64, 0, stream>>>(acc, (float*)d_out);
}

// Round 4
// 472.856 us; speedup vs baseline: 3.7013x; 1.7165x over previous
//
#include <hip/hip_runtime.h>
#include <cstdint>
#include <cstddef>

// ---------------- problem constants ----------------
// B=16, L=128, E=256, H=256, RR=128, BIO=64, NT=3, V=30000, R=25

typedef __attribute__((ext_vector_type(8))) short short8;
typedef __attribute__((ext_vector_type(4))) float f32x4;

__device__ __forceinline__ unsigned short f2bf(float f) {
  unsigned int u = __float_as_uint(f);
  u += 0x7fffu + ((u >> 16) & 1u);
  return (unsigned short)(u >> 16);
}
__device__ __forceinline__ float bf2f(unsigned short u) {
  return __uint_as_float(((unsigned int)u) << 16);
}

// ---------------- init: zero accumulators ----------------
__global__ void k_init(float* acc) {
  if (threadIdx.x < 16) acc[threadIdx.x] = 0.f;
}

// ---------------- embedding gather -> bf16 ----------------
__global__ void k_embed(const int* __restrict__ tok, const float* __restrict__ wemb,
                        unsigned short* __restrict__ emb16) {
  int bl = blockIdx.x;
  int t = threadIdx.x;
  int w = tok[bl];
  emb16[bl * 256 + t] = f2bf(wemb[(size_t)w * 256 + t]);
}

// ---------------- pre-pack W_hh (1024x256 f32) into fp8 MFMA B-frag layout ----------------
// frag f = nt*8+kt; lane holds 8 fp8 bytes: row = nt*16+(lane&15), k = kt*32+(lane>>4)*8 + j
__global__ void k_prepack8(const float* __restrict__ W, uint2* __restrict__ Wpk) {
  int idx = blockIdx.x * 256 + threadIdx.x; // 0..32767
  int lane = idx & 63;
  int kt = (idx >> 6) & 7;
  int nt = idx >> 9;
  int row = nt * 16 + (lane & 15);
  int k0 = kt * 32 + ((lane >> 4) << 3);
  const float* wp = &W[(size_t)row * 256 + k0];
  int lo = 0, hi = 0;
  lo = __builtin_amdgcn_cvt_pk_fp8_f32(wp[0], wp[1], lo, false);
  lo = __builtin_amdgcn_cvt_pk_fp8_f32(wp[2], wp[3], lo, true);
  hi = __builtin_amdgcn_cvt_pk_fp8_f32(wp[4], wp[5], hi, false);
  hi = __builtin_amdgcn_cvt_pk_fp8_f32(wp[6], wp[7], hi, true);
  uint2 r;
  r.x = (unsigned)lo;
  r.y = (unsigned)hi;
  Wpk[idx] = r;
}

// ---------------- pre-pack generic W (NxK f32, row stride ldw) into bf16 B-frag layout ----
// frag f = nt*nkt+kt; lane holds 8 bf16: row = nt*16+(lane&15), k = kt*32+(lane>>4)*8 + j
__global__ void k_prepackw(const float* __restrict__ W, int ldw, int nkt, int total,
                           uint4* __restrict__ out) {
  int idx = blockIdx.x * 256 + threadIdx.x;
  if (idx >= total) return;
  int lane = idx & 63;
  int f = idx >> 6;
  int kt = f % nkt;
  int nt = f / nkt;
  int row = nt * 16 + (lane & 15);
  int k0 = kt * 32 + ((lane >> 4) << 3);
  const float* wp = &W[(size_t)row * ldw + k0];
  union { unsigned short us[8]; uint4 v; } tmp;
#pragma unroll
  for (int j = 0; j < 8; ++j) tmp.us[j] = f2bf(wp[j]);
  out[idx] = tmp.v;
}

// ---------------- bf16 MFMA GEMM: C = act(A @ W^T + bias), bf16 in/out ----------------
// A: MxK bf16 row-major. Wpk: prepacked B-frags. 64x64 tile, 256 thr (4 waves),
// wave w owns m-tile w; no LDS. blockIdx.z selects (A,W,bias,C) pair.
template <bool RELU, bool BIAS>
__global__ __launch_bounds__(256) void k_bgemm(
    const unsigned short* __restrict__ A, const uint4* __restrict__ Wpk,
    const float* __restrict__ bias, unsigned short* __restrict__ C,
    const unsigned short* __restrict__ A2, const uint4* __restrict__ Wpk2,
    const float* __restrict__ bias2, unsigned short* __restrict__ C2,
    int M, int N, int K) {
  const unsigned short* Au = blockIdx.z ? A2 : A;
  const uint4* Wp = blockIdx.z ? Wpk2 : Wpk;
  const float* bi = blockIdx.z ? bias2 : bias;
  unsigned short* Co = blockIdx.z ? C2 : C;
  int nkt = K >> 5;
  int bn = blockIdx.x, bm = blockIdx.y;
  int tid = threadIdx.x;
  int w = tid >> 6;
  int lane = tid & 63;
  int m = lane & 15;
  int q = lane >> 4;
  int arow = bm * 64 + w * 16 + m;
  const unsigned short* Ap = Au + (size_t)arow * K + (q << 3);
  f32x4 z = {0.f, 0.f, 0.f, 0.f};
  f32x4 ac[4] = {z, z, z, z};
  for (int kt = 0; kt < nkt; ++kt) {
    uint4 a4 = *reinterpret_cast<const uint4*>(Ap + (kt << 5));
    short8 af = __builtin_bit_cast(short8, a4);
#pragma unroll
    for (int nt = 0; nt < 4; ++nt) {
      uint4 b4 = Wp[(size_t)(((bn << 2) + nt) * nkt + kt) * 64 + lane];
      ac[nt] = __builtin_amdgcn_mfma_f32_16x16x32_bf16(af, __builtin_bit_cast(short8, b4), ac[nt], 0, 0, 0);
    }
  }
#pragma unroll
  for (int nt = 0; nt < 4; ++nt) {
    int col = (bn << 6) + (nt << 4) + m;
    float bv = BIAS ? bi[col] : 0.f;
#pragma unroll
    for (int reg = 0; reg < 4; ++reg) {
      int row = (bm << 6) + (w << 4) + (q << 2) + reg;
      float v = ac[nt][reg] + bv;
      if (RELU) v = fmaxf(v, 0.f);
      Co[(size_t)row * N + col] = f2bf(v);
    }
  }
}

// ---------------- LSTM v4: 32 blocks = (dir, batch), 512 threads, fp8 W in VGPRs ----------
// Per block: one sequence's recurrence. Wave w owns gate n-tiles [w*8, w*8+8).
// W_hh (fp8, 256 KB) resident: 128 VGPR/lane. h (fp8) in LDS row 0 of a 16-row
// zeroed A-tile; gates cross waves via LDS transpose; nonlin on lanes 0..255.
__global__ __launch_bounds__(512, 2) void k_lstm4(
    const unsigned short* __restrict__ xgf16, const unsigned short* __restrict__ xgb16,
    const uint2* __restrict__ Wpk_f, const uint2* __restrict__ Wpk_b,
    float* __restrict__ hsf, float* __restrict__ hsb) {
  int bid = blockIdx.x;
  int dir = bid >> 4;
  int b = bid & 15;
  const unsigned short* xg = (dir ? xgb16 : xgf16) + (size_t)b * 128 * 1024;
  const uint2* Wpk = dir ? Wpk_b : Wpk_f;
  float* hseq = (dir ? hsb : hsf) + (size_t)b * 128 * 256;

  __shared__ __align__(8) unsigned char h8[16][264]; // A-tile rows; only row 0 live
  __shared__ float gbuf[1024];

  int tid = threadIdx.x;
  int w = tid >> 6;   // wave 0..7
  int lane = tid & 63;
  int m = lane & 15;
  int q = lane >> 4;

  // resident W: 8 ntiles x 8 kt = 64 uint2 = 128 VGPR/lane
  uint2 bfr[8][8];
#pragma unroll
  for (int ntl = 0; ntl < 8; ++ntl) {
#pragma unroll
    for (int kt = 0; kt < 8; ++kt)
      bfr[ntl][kt] = Wpk[(size_t)(((w << 3) + ntl) * 8 + kt) * 64 + lane];
  }

  // zero h8 (4224 B = 1056 dwords)
  for (int i = tid; i < 1056; i += 512) ((unsigned int*)&h8[0][0])[i] = 0;
  __syncthreads();

  float cstate = 0.f; // lanes tid<256 own c[j], j=tid

  for (int s = 0; s < 128; ++s) {
    int t = dir ? (127 - s) : s;

    // prefetch xg gate biases (bf16) for this step; consumed after barrier
    float x0 = 0.f, x1 = 0.f, x2 = 0.f, x3 = 0.f;
    if (tid < 256) {
      const unsigned short* xb = xg + (size_t)t * 1024 + tid;
      x0 = bf2f(xb[0]);
      x1 = bf2f(xb[256]);
      x2 = bf2f(xb[512]);
      x3 = bf2f(xb[768]);
    }

    // A-frags: lane row m, k = kt*32 + q*8 (8 fp8 bytes)
    const uint2* hrow = reinterpret_cast<const uint2*>(&h8[m][0]);
    long av[8];
#pragma unroll
    for (int kt = 0; kt < 8; ++kt)
      av[kt] = __builtin_bit_cast(long, hrow[(kt << 2) + q]);

    f32x4 zz = {0.f, 0.f, 0.f, 0.f};
    f32x4 ac[8] = {zz, zz, zz, zz, zz, zz, zz, zz};
#pragma unroll
    for (int kt = 0; kt < 8; ++kt) {
#pragma unroll
      for (int ntl = 0; ntl < 8; ++ntl)
        ac[ntl] = __builtin_amdgcn_mfma_f32_16x16x32_fp8_fp8(
            av[kt], __builtin_bit_cast(long, bfr[ntl][kt]), ac[ntl], 0, 0, 0);
    }

    // row 0 of each C-tile -> gbuf: lanes 0..15 hold (row0, col=lane) in reg 0
    if (lane < 16) {
#pragma unroll
      for (int ntl = 0; ntl < 8; ++ntl)
        gbuf[(w << 7) + (ntl << 4) + lane] = ac[ntl][0];
    }
    __syncthreads();

    if (tid < 256) {
      int j = tid;
      float gi = gbuf[j] + x0;
      float gf = gbuf[256 + j] + x1;
      float gg = gbuf[512 + j] + x2;
      float go = gbuf[768 + j] + x3;
      gi = fminf(fmaxf(gi, -30.f), 30.f);
      gf = fminf(fmaxf(gf, -30.f), 30.f);
      gg = fminf(fmaxf(gg, -30.f), 30.f);
      go = fminf(fmaxf(go, -30.f), 30.f);
      float si = __fdividef(1.f, 1.f + __expf(-gi));
      float sf = __fdividef(1.f, 1.f + __expf(-gf));
      float so = __fdividef(1.f, 1.f + __expf(-go));
      float eg = __expf(-2.f * gg);
      float tg = __fdividef(1.f - eg, 1.f + eg);
      float c = sf * cstate + si * tg;
      cstate = c;
      float cc = fminf(fmaxf(c, -30.f), 30.f);
      float ec = __expf(-2.f * cc);
      float th = __fdividef(1.f - ec, 1.f + ec);
      float h = so * th;
      hseq[(size_t)t * 256 + j] = h;
      int pk = __builtin_amdgcn_cvt_pk_fp8_f32(h, h, 0, false);
      h8[0][j] = (unsigned char)(pk & 0xff);
    }
    __syncthreads();
  }
}

// ---------------- o = 0.5*(hf+hb) f32; oc16 = bf16 concat(o, bio_emb[bio]) ----------------
__global__ void k_oc(const float* __restrict__ hf, const float* __restrict__ hb,
                     const int* __restrict__ bio, const float* __restrict__ bioE,
                     float* __restrict__ o, unsigned short* __restrict__ oc16) {
  int bl = blockIdx.x;
  int t = threadIdx.x; // 320
  if (t < 256) {
    float v = 0.5f * (hf[bl * 256 + t] + hb[bl * 256 + t]);
    o[bl * 256 + t] = v;
    oc16[bl * 320 + t] = f2bf(v);
  } else {
    oc16[bl * 320 + t] = f2bf(bioE[bio[bl] * 64 + (t - 256)]);
  }
}

// ---------------- emi = o @ emi_W^T + emi_b  (N=3) ----------------
__global__ void k_emi(const float* __restrict__ o, const float* __restrict__ emiW,
                      const float* __restrict__ emib, float* __restrict__ emi) {
  int bl = blockIdx.x;
  int t = threadIdx.x; // 64
  float p0 = 0.f, p1 = 0.f, p2 = 0.f;
  for (int k = t; k < 256; k += 64) {
    float ov = o[bl * 256 + k];
    p0 += ov * emiW[k];
    p1 += ov * emiW[256 + k];
    p2 += ov * emiW[512 + k];
  }
#pragma unroll
  for (int off = 32; off; off >>= 1) {
    p0 += __shfl_down(p0, off);
    p1 += __shfl_down(p1, off);
    p2 += __shfl_down(p2, off);
  }
  if (t == 0) {
    emi[bl * 3 + 0] = p0 + emib[0];
    emi[bl * 3 + 1] = p1 + emib[1];
    emi[bl * 3 + 2] = p2 + emib[2];
  }
}

// ---------------- fused selection loss (a,c now bf16) ----------------
__global__ __launch_bounds__(256) void k_sel(
    const unsigned short* __restrict__ a16, const unsigned short* __restrict__ c16,
    const float* __restrict__ suvb, const float* __restrict__ rel,
    const float* __restrict__ y, const int* __restrict__ tok,
    float* __restrict__ acc) {
  __shared__ unsigned short alds[128][136];
  __shared__ float cbs[2][128];
  __shared__ float red[4];
  int blk = blockIdx.x;
  int b = blk >> 6;
  int ip = blk & 63;
  int tid = threadIdx.x;
  int hh = tid & 127;
  int half = tid >> 7;
  for (int j2 = half; j2 < 128; j2 += 2)
    alds[hh][j2] = a16[(size_t)((b << 7) + j2) * 128 + hh];
  {
    int i = (ip << 1) + half;
    cbs[half][hh] = bf2f(c16[(size_t)((b << 7) + i) * 128 + hh]) + suvb[hh];
  }
  __syncthreads();
  int i = (ip << 1) + half;
  int j = hh;
  float lg[25];
#pragma unroll
  for (int r = 0; r < 25; ++r) lg[r] = 0.f;
  for (int h = 0; h < 128; ++h) {
    float av = bf2f(alds[h][j]);
    float uv = fmaxf(av + cbs[half][h], 0.f);
#pragma unroll
    for (int r = 0; r < 25; ++r) lg[r] += uv * rel[r * 128 + h];
  }
  float mi = (tok[(b << 7) + i] != 0) ? 1.f : 0.f;
  float mj = (tok[(b << 7) + j] != 0) ? 1.f : 0.f;
  const float* yp = y + (size_t)((b << 7) + i) * 3200 + j;
  float bs = 0.f;
#pragma unroll
  for (int r = 0; r < 25; ++r) {
    float x = lg[r];
    float yv = yp[r * 128];
    bs += fmaxf(x, 0.f) - x * yv + log1pf(__expf(-fabsf(x)));
  }
  bs *= mi * mj;
#pragma unroll
  for (int off = 32; off; off >>= 1) bs += __shfl_down(bs, off);
  if ((tid & 63) == 0) red[tid >> 6] = bs;
  __syncthreads();
  if (tid == 0) atomicAdd(&acc[0], red[0] + red[1] + red[2] + red[3]);
}

// ---------------- CRF loss (num & den) per batch ----------------
__global__ __launch_bounds__(128) void k_crf(
    const float* __restrict__ emi, const int* __restrict__ bio, const int* __restrict__ tok,
    const float* __restrict__ cstart, const float* __restrict__ cend,
    const float* __restrict__ ctrans, float* __restrict__ acc) {
  int b = blockIdx.x;
  int t = threadIdx.x;
  __shared__ float elds[128][4];
  __shared__ float msk[128];
  __shared__ int biol[128];
  __shared__ float r_t[2], r_m[2];
  biol[t] = bio[b * 128 + t];
  msk[t] = (tok[b * 128 + t] != 0) ? 1.f : 0.f;
#pragma unroll
  for (int g = 0; g < 3; ++g) elds[t][g] = emi[(b * 128 + t) * 3 + g];
  __syncthreads();
  float m = msk[t];
  float term;
  if (t == 0)
    term = cstart[biol[0]] + elds[0][biol[0]];
  else
    term = (ctrans[biol[t - 1] * 3 + biol[t]] + elds[t][biol[t]]) * m;
  float ms = m;
#pragma unroll
  for (int off = 32; off; off >>= 1) {
    term += __shfl_down(term, off);
    ms += __shfl_down(ms, off);
  }
  if ((t & 63) == 0) { r_t[t >> 6] = term; r_m[t >> 6] = ms; }
  __syncthreads();
  if (t == 0) {
    float num = r_t[0] + r_t[1];
    float msum = r_m[0] + r_m[1];
    int se = (int)msum - 1;
    if (se < 0) se = 0;
    num += cend[biol[se]];
    float tr[9];
#pragma unroll
    for (int i2 = 0; i2 < 9; ++i2) tr[i2] = ctrans[i2];
    float s0 = cstart[0] + elds[0][0];
    float s1 = cstart[1] + elds[0][1];
    float s2 = cstart[2] + elds[0][2];
    for (int tt = 1; tt < 128; ++tt) {
      float a0, a1, a2, mx, n0, n1, n2;
      a0 = s0 + tr[0]; a1 = s1 + tr[3]; a2 = s2 + tr[6];
      mx = fmaxf(a0, fmaxf(a1, a2));
      n0 = mx + __logf(__expf(a0 - mx) + __expf(a1 - mx) + __expf(a2 - mx)) + elds[tt][0];
      a0 = s0 + tr[1]; a1 = s1 + tr[4]; a2 = s2 + tr[7];
      mx = fmaxf(a0, fmaxf(a1, a2));
      n1 = mx + __logf(__expf(a0 - mx) + __expf(a1 - mx) + __expf(a2 - mx)) + elds[tt][1];
      a0 = s0 + tr[2]; a1 = s1 + tr[5]; a2 = s2 + tr[8];
      mx = fmaxf(a0, fmaxf(a1, a2));
      n2 = mx + __logf(__expf(a0 - mx) + __expf(a1 - mx) + __expf(a2 - mx)) + elds[tt][2];
      if (msk[tt] != 0.f) { s0 = n0; s1 = n1; s2 = n2; }
    }
    float a0 = s0 + cend[0], a1 = s1 + cend[1], a2 = s2 + cend[2];
    float mx = fmaxf(a0, fmaxf(a1, a2));
    float den = mx + __logf(__expf(a0 - mx) + __expf(a1 - mx) + __expf(a2 - mx));
    atomicAdd(&acc[1], num - den);
    atomicAdd(&acc[2], msum);
  }
}

// ---------------- finalize ----------------
__global__ void k_fin(const float* __restrict__ acc, float* __restrict__ out) {
  if (threadIdx.x == 0 && blockIdx.x == 0)
    out[0] = -(acc[1] * (1.f / 16.f)) + acc[0] / acc[2];
}

// ---------------- host launcher ----------------
extern "C" void kernel_launch(void* const* d_in, const int* in_sizes, int n_in,
                              void* d_out, int out_size, void* d_ws, size_t ws_size,
                              hipStream_t stream) {
  const int* tokens = (const int*)d_in[0];
  const int* bio = (const int*)d_in[1];
  const float* selg = (const float*)d_in[2];
  const float* wemb = (const float*)d_in[3];
  const float* Wihf = (const float*)d_in[4];
  const float* Whhf = (const float*)d_in[5];
  const float* bf = (const float*)d_in[6];
  const float* Wihb = (const float*)d_in[7];
  const float* Whhb = (const float*)d_in[8];
  const float* bb = (const float*)d_in[9];
  const float* emiW = (const float*)d_in[10];
  const float* emib = (const float*)d_in[11];
  const float* bioE = (const float*)d_in[12];
  const float* suW = (const float*)d_in[13];
  const float* sub = (const float*)d_in[14];
  const float* svW = (const float*)d_in[15];
  const float* svb = (const float*)d_in[16];
  const float* suvW = (const float*)d_in[17];
  const float* suvb = (const float*)d_in[18];
  const float* rel = (const float*)d_in[19];
  const float* cstart = (const float*)d_in[20];
  const float* cend = (const float*)d_in[21];
  const float* ctrans = (const float*)d_in[22];

  float* ws = (float*)d_ws;
  float* emb16 = ws;                         // 262144 f (2048x256 bf16)
  float* xgf16 = emb16 + 262144;             // 1048576 f (2048x1024 bf16)
  float* xgb16 = xgf16 + 1048576;            // 1048576
  float* hf = xgb16 + 1048576;               // 524288 f32
  float* hb = hf + 524288;                   // 524288
  float* o = hb + 524288;                    // 524288
  float* oc16 = o + 524288;                  // 327680 f (2048x320 bf16)
  float* u16 = oc16 + 327680;                // 131072 f (2048x128 bf16)
  float* v16 = u16 + 131072;                 // 131072
  float* a16 = v16 + 131072;                 // 131072
  float* c16 = a16 + 131072;                 // 131072
  float* emi = c16 + 131072;                 // 6144
  float* wpk8f = emi + 6144;                 // 65536 f (256 KB fp8 frags)
  float* wpk8b = wpk8f + 65536;              // 65536
  float* wihfPk = wpk8b + 65536;             // 131072 f (bf16 frags 1024x256)
  float* wihbPk = wihfPk + 131072;           // 131072
  float* suPk = wihbPk + 131072;             // 20480 f (128x320)
  float* svPk = suPk + 20480;                // 20480
  float* w1Pk = svPk + 20480;                // 8192 f (128x128)
  float* w2Pk = w1Pk + 8192;                 // 8192
  float* acc = w2Pk + 8192;                  // 16

  k_init<<<1, 64, 0, stream>>>(acc);
  k_embed<<<2048, 256, 0, stream>>>(tokens, wemb, (unsigned short*)emb16);
  k_prepack8<<<128, 256, 0, stream>>>(Whhf, (uint2*)wpk8f);
  k_prepack8<<<128, 256, 0, stream>>>(Whhb, (uint2*)wpk8b);
  k_prepackw<<<128, 256, 0, stream>>>(Wihf, 256, 8, 32768, (uint4*)wihfPk);
  k_prepackw<<<128, 256, 0, stream>>>(Wihb, 256, 8, 32768, (uint4*)wihbPk);
  k_prepackw<<<20, 256, 0, stream>>>(suW, 320, 10, 5120, (uint4*)suPk);
  k_prepackw<<<20, 256, 0, stream>>>(svW, 320, 10, 5120, (uint4*)svPk);
  k_prepackw<<<8, 256, 0, stream>>>(suvW, 256, 4, 2048, (uint4*)w1Pk);
  k_prepackw<<<8, 256, 0, stream>>>(suvW + 128, 256, 4, 2048, (uint4*)w2Pk);

  // xg = emb @ W_ih^T + b  (both dirs via z)
  k_bgemm<false, true><<<dim3(16, 32, 2), 256, 0, stream>>>(
      (const unsigned short*)emb16, (const uint4*)wihfPk, bf, (unsigned short*)xgf16,
      (const unsigned short*)emb16, (const uint4*)wihbPk, bb, (unsigned short*)xgb16,
      2048, 1024, 256);

  k_lstm4<<<32, 512, 0, stream>>>((const unsigned short*)xgf16, (const unsigned short*)xgb16,
                                  (const uint2*)wpk8f, (const uint2*)wpk8b, hf, hb);

  k_oc<<<2048, 320, 0, stream>>>(hf, hb, bio, bioE, o, (unsigned short*)oc16);
  k_emi<<<2048, 64, 0, stream>>>(o, emiW, emib, emi);

  // u = relu(oc@suW^T+sub), v = relu(oc@svW^T+svb)
  k_bgemm<true, true><<<dim3(2, 32, 2), 256, 0, stream>>>(
      (const unsigned short*)oc16, (const uint4*)suPk, sub, (unsigned short*)u16,
      (const unsigned short*)oc16, (const uint4*)svPk, svb, (unsigned short*)v16,
      2048, 128, 320);

  // a = u@W1^T, c = v@W2^T
  k_bgemm<false, false><<<dim3(2, 32, 2), 256, 0, stream>>>(
      (const unsigned short*)u16, (const uint4*)w1Pk, nullptr, (unsigned short*)a16,
      (const unsigned short*)v16, (const uint4*)w2Pk, nullptr, (unsigned short*)c16,
      2048, 128, 128);

  k_sel<<<1024, 256, 0, stream>>>((const unsigned short*)a16, (const unsigned short*)c16,
                                  suvb, rel, selg, tokens, acc);
  k_crf<<<16, 128, 0, stream>>>(emi, bio, tokens, cstart, cend, ctrans, acc);
  k_fin<<<1, 64, 0, stream>>>(acc, (float*)d_out);
}

// Round 5
// 455.746 us; speedup vs baseline: 3.8403x; 1.0375x over previous
//
#include <hip/hip_runtime.h>
#include <cstdint>
#include <cstddef>

// ---------------- problem constants ----------------
// B=16, L=128, E=256, H=256, RR=128, BIO=64, NT=3, V=30000, R=25

typedef __attribute__((ext_vector_type(8))) short short8;
typedef __attribute__((ext_vector_type(4))) float f32x4;

__device__ __forceinline__ unsigned short f2bf(float f) {
  unsigned int u = __float_as_uint(f);
  u += 0x7fffu + ((u >> 16) & 1u);
  return (unsigned short)(u >> 16);
}
__device__ __forceinline__ float bf2f(unsigned short u) {
  return __uint_as_float(((unsigned int)u) << 16);
}

// ---------------- fused setup: embed + all weight prepacks + acc init ----------------
__device__ __forceinline__ void dev_pp8(const float* __restrict__ W, uint2* __restrict__ Wpk,
                                        int idx) {
  int lane = idx & 63;
  int kt = (idx >> 6) & 7;
  int nt = idx >> 9;
  int row = nt * 16 + (lane & 15);
  int k0 = kt * 32 + ((lane >> 4) << 3);
  const float* wp = &W[(size_t)row * 256 + k0];
  int lo = 0, hi = 0;
  lo = __builtin_amdgcn_cvt_pk_fp8_f32(wp[0], wp[1], lo, false);
  lo = __builtin_amdgcn_cvt_pk_fp8_f32(wp[2], wp[3], lo, true);
  hi = __builtin_amdgcn_cvt_pk_fp8_f32(wp[4], wp[5], hi, false);
  hi = __builtin_amdgcn_cvt_pk_fp8_f32(wp[6], wp[7], hi, true);
  uint2 r;
  r.x = (unsigned)lo;
  r.y = (unsigned)hi;
  Wpk[idx] = r;
}

__device__ __forceinline__ void dev_ppw(const float* __restrict__ W, int ldw, int nkt,
                                        uint4* __restrict__ out, int idx) {
  int lane = idx & 63;
  int f = idx >> 6;
  int kt = f % nkt;
  int nt = f / nkt;
  int row = nt * 16 + (lane & 15);
  int k0 = kt * 32 + ((lane >> 4) << 3);
  const float* wp = &W[(size_t)row * ldw + k0];
  union { unsigned short us[8]; uint4 v; } tmp;
#pragma unroll
  for (int j = 0; j < 8; ++j) tmp.us[j] = f2bf(wp[j]);
  out[idx] = tmp.v;
}

__global__ __launch_bounds__(256) void k_setup(
    const int* __restrict__ tok, const float* __restrict__ wemb,
    unsigned short* __restrict__ emb16,
    const float* __restrict__ Whhf, uint2* __restrict__ wpk8f,
    const float* __restrict__ Whhb, uint2* __restrict__ wpk8b,
    const float* __restrict__ Wihf, uint4* __restrict__ wihfPk,
    const float* __restrict__ Wihb, uint4* __restrict__ wihbPk,
    const float* __restrict__ suW, uint4* __restrict__ suPk,
    const float* __restrict__ svW, uint4* __restrict__ svPk,
    const float* __restrict__ suvW, uint4* __restrict__ w1Pk, uint4* __restrict__ w2Pk,
    float* __restrict__ acc) {
  int bid = blockIdx.x;
  int t = threadIdx.x;
  if (bid < 2048) {
    int w = tok[bid];
    emb16[bid * 256 + t] = f2bf(wemb[(size_t)w * 256 + t]);
  } else if (bid < 2176) {
    dev_pp8(Whhf, wpk8f, (bid - 2048) * 256 + t);
  } else if (bid < 2304) {
    dev_pp8(Whhb, wpk8b, (bid - 2176) * 256 + t);
  } else if (bid < 2432) {
    dev_ppw(Wihf, 256, 8, wihfPk, (bid - 2304) * 256 + t);
  } else if (bid < 2560) {
    dev_ppw(Wihb, 256, 8, wihbPk, (bid - 2432) * 256 + t);
  } else if (bid < 2580) {
    dev_ppw(suW, 320, 10, suPk, (bid - 2560) * 256 + t);
  } else if (bid < 2600) {
    dev_ppw(svW, 320, 10, svPk, (bid - 2580) * 256 + t);
  } else if (bid < 2608) {
    dev_ppw(suvW, 256, 4, w1Pk, (bid - 2600) * 256 + t);
  } else if (bid < 2616) {
    dev_ppw(suvW + 128, 256, 4, w2Pk, (bid - 2608) * 256 + t);
  } else {
    if (t < 16) acc[t] = 0.f;
  }
}

// ---------------- bf16 MFMA GEMM: C = act(A @ W^T + bias), bf16 in/out ----------------
template <bool RELU, bool BIAS>
__global__ __launch_bounds__(256) void k_bgemm(
    const unsigned short* __restrict__ A, const uint4* __restrict__ Wpk,
    const float* __restrict__ bias, unsigned short* __restrict__ C,
    const unsigned short* __restrict__ A2, const uint4* __restrict__ Wpk2,
    const float* __restrict__ bias2, unsigned short* __restrict__ C2,
    int M, int N, int K) {
  const unsigned short* Au = blockIdx.z ? A2 : A;
  const uint4* Wp = blockIdx.z ? Wpk2 : Wpk;
  const float* bi = blockIdx.z ? bias2 : bias;
  unsigned short* Co = blockIdx.z ? C2 : C;
  int nkt = K >> 5;
  int bn = blockIdx.x, bm = blockIdx.y;
  int tid = threadIdx.x;
  int w = tid >> 6;
  int lane = tid & 63;
  int m = lane & 15;
  int q = lane >> 4;
  int arow = bm * 64 + w * 16 + m;
  const unsigned short* Ap = Au + (size_t)arow * K + (q << 3);
  f32x4 z = {0.f, 0.f, 0.f, 0.f};
  f32x4 ac[4] = {z, z, z, z};
  for (int kt = 0; kt < nkt; ++kt) {
    uint4 a4 = *reinterpret_cast<const uint4*>(Ap + (kt << 5));
    short8 af = __builtin_bit_cast(short8, a4);
#pragma unroll
    for (int nt = 0; nt < 4; ++nt) {
      uint4 b4 = Wp[(size_t)(((bn << 2) + nt) * nkt + kt) * 64 + lane];
      ac[nt] = __builtin_amdgcn_mfma_f32_16x16x32_bf16(af, __builtin_bit_cast(short8, b4), ac[nt], 0, 0, 0);
    }
  }
#pragma unroll
  for (int nt = 0; nt < 4; ++nt) {
    int col = (bn << 6) + (nt << 4) + m;
    float bv = BIAS ? bi[col] : 0.f;
#pragma unroll
    for (int reg = 0; reg < 4; ++reg) {
      int row = (bm << 6) + (w << 4) + (q << 2) + reg;
      float v = ac[nt][reg] + bv;
      if (RELU) v = fmaxf(v, 0.f);
      Co[(size_t)row * N + col] = f2bf(v);
    }
  }
}

// ---------------- LSTM v5: 32 blocks = (dir, batch), 512 threads ----------------
// Wave w owns hidden j in [w*32, w*32+32) for ALL 4 gates: tiles nt = g*16 + 2w + d.
// W_hh fp8 resident in VGPRs (128/lane), pinned via asm so the compiler cannot
// rematerialize the loads (round-4 failure: VGPR=92 proved reload-per-step).
// Gate transpose via in-wave shfl (row 0 of C lives in lanes 0..15 reg 0).
// A-frags: only m==0 lanes read h from LDS; other rows are structurally zero.
// h double-buffered in 512 B LDS -> ONE barrier per step.
__global__ __launch_bounds__(512, 2) void k_lstm5(
    const unsigned short* __restrict__ xgf16, const unsigned short* __restrict__ xgb16,
    const uint2* __restrict__ Wpk_f, const uint2* __restrict__ Wpk_b,
    unsigned short* __restrict__ hsf16, unsigned short* __restrict__ hsb16) {
  int bid = blockIdx.x;
  int dir = bid >> 4;
  int b = bid & 15;
  const unsigned short* xg = (dir ? xgb16 : xgf16) + (size_t)b * 128 * 1024;
  const uint2* Wpk = dir ? Wpk_b : Wpk_f;
  unsigned short* hseq = (dir ? hsb16 : hsf16) + (size_t)b * 128 * 256;

  __shared__ __align__(8) unsigned char hbuf[2][256];

  int tid = threadIdx.x;
  int w = tid >> 6;   // wave 0..7
  int lane = tid & 63;
  int m = lane & 15;
  int q = lane >> 4;

  // resident W: gate g (0..3), dtile d (0..1): nt = g*16 + 2w + d; 64 uint2 = 128 VGPR
  uint2 bfr[4][2][8];
#pragma unroll
  for (int g = 0; g < 4; ++g)
#pragma unroll
    for (int d = 0; d < 2; ++d)
#pragma unroll
      for (int kt = 0; kt < 8; ++kt)
        bfr[g][d][kt] = Wpk[(size_t)(((g * 16 + 2 * w + d) * 8) + kt) * 64 + lane];
  // pin: compiler must keep these in VGPRs (cannot re-derive from memory)
#pragma unroll
  for (int g = 0; g < 4; ++g)
#pragma unroll
    for (int d = 0; d < 2; ++d)
#pragma unroll
      for (int kt = 0; kt < 8; ++kt)
        asm volatile("" : "+v"(bfr[g][d][kt].x), "+v"(bfr[g][d][kt].y));

  if (tid < 128) ((unsigned int*)&hbuf[0][0])[tid] = 0;
  __syncthreads();

  float cstate = 0.f;          // lanes 0..31 of each wave own j = w*32 + lane
  int j = (w << 5) + lane;     // valid when lane < 32

  for (int s = 0; s < 128; ++s) {
    int t = dir ? (127 - s) : s;
    const unsigned char* cur = hbuf[s & 1];
    unsigned char* nxt = hbuf[(s & 1) ^ 1];

    // xg gate biases (independent of h; overlaps with MFMA)
    float x0 = 0.f, x1 = 0.f, x2 = 0.f, x3 = 0.f;
    if (lane < 32) {
      const unsigned short* xb = xg + (size_t)t * 1024 + j;
      x0 = bf2f(xb[0]);
      x1 = bf2f(xb[256]);
      x2 = bf2f(xb[512]);
      x3 = bf2f(xb[768]);
    }

    // A-frags: row m==0 lanes carry h; all other rows are zero
    long av[8];
    if (m == 0) {
      const uint2* hr = reinterpret_cast<const uint2*>(cur);
#pragma unroll
      for (int kt = 0; kt < 8; ++kt)
        av[kt] = __builtin_bit_cast(long, hr[(kt << 2) + q]);
    } else {
#pragma unroll
      for (int kt = 0; kt < 8; ++kt) av[kt] = 0;
    }

    f32x4 zz = {0.f, 0.f, 0.f, 0.f};
    f32x4 ac[4][2] = {{zz, zz}, {zz, zz}, {zz, zz}, {zz, zz}};
#pragma unroll
    for (int kt = 0; kt < 8; ++kt) {
#pragma unroll
      for (int g = 0; g < 4; ++g) {
        ac[g][0] = __builtin_amdgcn_mfma_f32_16x16x32_fp8_fp8(
            av[kt], __builtin_bit_cast(long, bfr[g][0][kt]), ac[g][0], 0, 0, 0);
        ac[g][1] = __builtin_amdgcn_mfma_f32_16x16x32_fp8_fp8(
            av[kt], __builtin_bit_cast(long, bfr[g][1][kt]), ac[g][1], 0, 0, 0);
      }
    }

    // gate extraction: row0 col c is reg 0 of lane c (c=0..15); in-wave shfl
    if (lane < 32) {
      float gv[4];
#pragma unroll
      for (int g = 0; g < 4; ++g) {
        float va = __shfl(ac[g][0][0], m);
        float vb = __shfl(ac[g][1][0], m);
        gv[g] = (lane & 16) ? vb : va;
      }
      float gi = gv[0] + x0;
      float gf = gv[1] + x1;
      float gg = gv[2] + x2;
      float go = gv[3] + x3;
      gi = fminf(fmaxf(gi, -30.f), 30.f);
      gf = fminf(fmaxf(gf, -30.f), 30.f);
      gg = fminf(fmaxf(gg, -30.f), 30.f);
      go = fminf(fmaxf(go, -30.f), 30.f);
      float si = __fdividef(1.f, 1.f + __expf(-gi));
      float sf = __fdividef(1.f, 1.f + __expf(-gf));
      float so = __fdividef(1.f, 1.f + __expf(-go));
      float eg = __expf(-2.f * gg);
      float tg = __fdividef(1.f - eg, 1.f + eg);
      float c = sf * cstate + si * tg;
      cstate = c;
      float cc = fminf(fmaxf(c, -30.f), 30.f);
      float ec = __expf(-2.f * cc);
      float th = __fdividef(1.f - ec, 1.f + ec);
      float h = so * th;
      hseq[(size_t)t * 256 + j] = f2bf(h);
      int pk = __builtin_amdgcn_cvt_pk_fp8_f32(h, h, 0, false);
      nxt[j] = (unsigned char)(pk & 0xff);
    }
    __syncthreads();
  }
}

// ---------------- fused o/oc/emi: one block per (b,l) ----------------
__global__ __launch_bounds__(256) void k_ocemi(
    const unsigned short* __restrict__ hf16, const unsigned short* __restrict__ hb16,
    const int* __restrict__ bio, const float* __restrict__ bioE,
    const float* __restrict__ emiW, const float* __restrict__ emib,
    unsigned short* __restrict__ oc16, float* __restrict__ emi) {
  __shared__ float ol[256];
  int bl = blockIdx.x;
  int t = threadIdx.x;
  float v = 0.5f * (bf2f(hf16[bl * 256 + t]) + bf2f(hb16[bl * 256 + t]));
  ol[t] = v;
  oc16[bl * 320 + t] = f2bf(v);
  if (t < 64) oc16[bl * 320 + 256 + t] = f2bf(bioE[bio[bl] * 64 + t]);
  __syncthreads();
  if (t < 64) {
    float p0 = 0.f, p1 = 0.f, p2 = 0.f;
    for (int k = t; k < 256; k += 64) {
      float ov = ol[k];
      p0 += ov * emiW[k];
      p1 += ov * emiW[256 + k];
      p2 += ov * emiW[512 + k];
    }
#pragma unroll
    for (int off = 32; off; off >>= 1) {
      p0 += __shfl_down(p0, off);
      p1 += __shfl_down(p1, off);
      p2 += __shfl_down(p2, off);
    }
    if (t == 0) {
      emi[bl * 3 + 0] = p0 + emib[0];
      emi[bl * 3 + 1] = p1 + emib[1];
      emi[bl * 3 + 2] = p2 + emib[2];
    }
  }
}

// ---------------- fused loss: sel (blocks 0..1023) + crf (1024..1039) + finalize ----------------
__global__ __launch_bounds__(256) void k_loss(
    const unsigned short* __restrict__ a16, const unsigned short* __restrict__ c16,
    const float* __restrict__ suvb, const float* __restrict__ rel,
    const float* __restrict__ y, const int* __restrict__ tok,
    const float* __restrict__ emi, const int* __restrict__ bio,
    const float* __restrict__ cstart, const float* __restrict__ cend,
    const float* __restrict__ ctrans,
    float* __restrict__ acc, float* __restrict__ out) {
  int blk = blockIdx.x;
  int tid = threadIdx.x;
  if (blk < 1024) {
    // ---- selection loss ----
    __shared__ unsigned short alds[128][136];
    __shared__ float cbs[2][128];
    __shared__ float red[4];
    int b = blk >> 6;
    int ip = blk & 63;
    int hh = tid & 127;
    int half = tid >> 7;
    for (int j2 = half; j2 < 128; j2 += 2)
      alds[hh][j2] = a16[(size_t)((b << 7) + j2) * 128 + hh];
    {
      int i = (ip << 1) + half;
      cbs[half][hh] = bf2f(c16[(size_t)((b << 7) + i) * 128 + hh]) + suvb[hh];
    }
    __syncthreads();
    int i = (ip << 1) + half;
    int j = hh;
    float lg[25];
#pragma unroll
    for (int r = 0; r < 25; ++r) lg[r] = 0.f;
    for (int h = 0; h < 128; ++h) {
      float av = bf2f(alds[h][j]);
      float uv = fmaxf(av + cbs[half][h], 0.f);
#pragma unroll
      for (int r = 0; r < 25; ++r) lg[r] += uv * rel[r * 128 + h];
    }
    float mi = (tok[(b << 7) + i] != 0) ? 1.f : 0.f;
    float mj = (tok[(b << 7) + j] != 0) ? 1.f : 0.f;
    const float* yp = y + (size_t)((b << 7) + i) * 3200 + j;
    float bs = 0.f;
#pragma unroll
    for (int r = 0; r < 25; ++r) {
      float x = lg[r];
      float yv = yp[r * 128];
      bs += fmaxf(x, 0.f) - x * yv + __logf(1.f + __expf(-fabsf(x)));
    }
    bs *= mi * mj;
#pragma unroll
    for (int off = 32; off; off >>= 1) bs += __shfl_down(bs, off);
    if ((tid & 63) == 0) red[tid >> 6] = bs;
    __syncthreads();
    if (tid == 0) atomicAdd(&acc[0], red[0] + red[1] + red[2] + red[3]);
  } else {
    // ---- CRF loss (one block per batch) ----
    __shared__ float elds[128][4];
    __shared__ float msk[128];
    __shared__ int biol[128];
    __shared__ float r_t[2], r_m[2];
    int b = blk - 1024;
    int t = tid;
    if (t < 128) {
      biol[t] = bio[b * 128 + t];
      msk[t] = (tok[b * 128 + t] != 0) ? 1.f : 0.f;
#pragma unroll
      for (int g = 0; g < 3; ++g) elds[t][g] = emi[(b * 128 + t) * 3 + g];
    }
    __syncthreads();
    if (t < 128) {
      float m = msk[t];
      float term;
      if (t == 0)
        term = cstart[biol[0]] + elds[0][biol[0]];
      else
        term = (ctrans[biol[t - 1] * 3 + biol[t]] + elds[t][biol[t]]) * m;
      float ms = m;
#pragma unroll
      for (int off = 32; off; off >>= 1) {
        term += __shfl_down(term, off);
        ms += __shfl_down(ms, off);
      }
      if ((t & 63) == 0) { r_t[t >> 6] = term; r_m[t >> 6] = ms; }
    }
    __syncthreads();
    if (t == 0) {
      float num = r_t[0] + r_t[1];
      float msum = r_m[0] + r_m[1];
      int se = (int)msum - 1;
      if (se < 0) se = 0;
      num += cend[biol[se]];
      float tr[9];
#pragma unroll
      for (int i2 = 0; i2 < 9; ++i2) tr[i2] = ctrans[i2];
      float s0 = cstart[0] + elds[0][0];
      float s1 = cstart[1] + elds[0][1];
      float s2 = cstart[2] + elds[0][2];
      for (int tt = 1; tt < 128; ++tt) {
        float a0, a1, a2, mx, n0, n1, n2;
        a0 = s0 + tr[0]; a1 = s1 + tr[3]; a2 = s2 + tr[6];
        mx = fmaxf(a0, fmaxf(a1, a2));
        n0 = mx + __logf(__expf(a0 - mx) + __expf(a1 - mx) + __expf(a2 - mx)) + elds[tt][0];
        a0 = s0 + tr[1]; a1 = s1 + tr[4]; a2 = s2 + tr[7];
        mx = fmaxf(a0, fmaxf(a1, a2));
        n1 = mx + __logf(__expf(a0 - mx) + __expf(a1 - mx) + __expf(a2 - mx)) + elds[tt][1];
        a0 = s0 + tr[2]; a1 = s1 + tr[5]; a2 = s2 + tr[8];
        mx = fmaxf(a0, fmaxf(a1, a2));
        n2 = mx + __logf(__expf(a0 - mx) + __expf(a1 - mx) + __expf(a2 - mx)) + elds[tt][2];
        if (msk[tt] != 0.f) { s0 = n0; s1 = n1; s2 = n2; }
      }
      float a0 = s0 + cend[0], a1 = s1 + cend[1], a2 = s2 + cend[2];
      float mx = fmaxf(a0, fmaxf(a1, a2));
      float den = mx + __logf(__expf(a0 - mx) + __expf(a1 - mx) + __expf(a2 - mx));
      atomicAdd(&acc[1], num - den);
      atomicAdd(&acc[2], msum);
    }
  }
  // ---- finalize: last block to finish computes the scalar output ----
  if (tid == 0) {
    __threadfence();
    unsigned old = atomicAdd((unsigned int*)(acc + 5), 1u);
    if (old == 1039u) {
      __threadfence();
      float s0 = atomicAdd(&acc[0], 0.f);
      float s1 = atomicAdd(&acc[1], 0.f);
      float s2 = atomicAdd(&acc[2], 0.f);
      out[0] = -(s1 * (1.f / 16.f)) + s0 / s2;
    }
  }
}

// ---------------- host launcher ----------------
extern "C" void kernel_launch(void* const* d_in, const int* in_sizes, int n_in,
                              void* d_out, int out_size, void* d_ws, size_t ws_size,
                              hipStream_t stream) {
  const int* tokens = (const int*)d_in[0];
  const int* bio = (const int*)d_in[1];
  const float* selg = (const float*)d_in[2];
  const float* wemb = (const float*)d_in[3];
  const float* Wihf = (const float*)d_in[4];
  const float* Whhf = (const float*)d_in[5];
  const float* bf = (const float*)d_in[6];
  const float* Wihb = (const float*)d_in[7];
  const float* Whhb = (const float*)d_in[8];
  const float* bb = (const float*)d_in[9];
  const float* emiW = (const float*)d_in[10];
  const float* emib = (const float*)d_in[11];
  const float* bioE = (const float*)d_in[12];
  const float* suW = (const float*)d_in[13];
  const float* sub = (const float*)d_in[14];
  const float* svW = (const float*)d_in[15];
  const float* svb = (const float*)d_in[16];
  const float* suvW = (const float*)d_in[17];
  const float* suvb = (const float*)d_in[18];
  const float* rel = (const float*)d_in[19];
  const float* cstart = (const float*)d_in[20];
  const float* cend = (const float*)d_in[21];
  const float* ctrans = (const float*)d_in[22];

  float* ws = (float*)d_ws;
  float* emb16 = ws;                         // 262144 f (2048x256 bf16)
  float* xgf16 = emb16 + 262144;             // 1048576 f (2048x1024 bf16)
  float* xgb16 = xgf16 + 1048576;            // 1048576
  float* hf16 = xgb16 + 1048576;             // 262144 f (2048x256 bf16)
  float* hb16 = hf16 + 262144;               // 262144
  float* oc16 = hb16 + 262144;               // 327680 f (2048x320 bf16)
  float* u16 = oc16 + 327680;                // 131072 f (2048x128 bf16)
  float* v16 = u16 + 131072;                 // 131072
  float* a16 = v16 + 131072;                 // 131072
  float* c16 = a16 + 131072;                 // 131072
  float* emi = c16 + 131072;                 // 6144
  float* wpk8f = emi + 6144;                 // 65536 f (256 KB fp8 frags)
  float* wpk8b = wpk8f + 65536;              // 65536
  float* wihfPk = wpk8b + 65536;             // 131072 f (bf16 frags 1024x256)
  float* wihbPk = wihfPk + 131072;           // 131072
  float* suPk = wihbPk + 131072;             // 20480 f (128x320)
  float* svPk = suPk + 20480;                // 20480
  float* w1Pk = svPk + 20480;                // 8192 f (128x128)
  float* w2Pk = w1Pk + 8192;                 // 8192
  float* acc = w2Pk + 8192;                  // 16 (sums + completion counter)

  k_setup<<<2617, 256, 0, stream>>>(
      tokens, wemb, (unsigned short*)emb16,
      Whhf, (uint2*)wpk8f, Whhb, (uint2*)wpk8b,
      Wihf, (uint4*)wihfPk, Wihb, (uint4*)wihbPk,
      suW, (uint4*)suPk, svW, (uint4*)svPk,
      suvW, (uint4*)w1Pk, (uint4*)w2Pk, acc);

  // xg = emb @ W_ih^T + b  (both dirs via z)
  k_bgemm<false, true><<<dim3(16, 32, 2), 256, 0, stream>>>(
      (const unsigned short*)emb16, (const uint4*)wihfPk, bf, (unsigned short*)xgf16,
      (const unsigned short*)emb16, (const uint4*)wihbPk, bb, (unsigned short*)xgb16,
      2048, 1024, 256);

  k_lstm5<<<32, 512, 0, stream>>>((const unsigned short*)xgf16, (const unsigned short*)xgb16,
                                  (const uint2*)wpk8f, (const uint2*)wpk8b,
                                  (unsigned short*)hf16, (unsigned short*)hb16);

  k_ocemi<<<2048, 256, 0, stream>>>((const unsigned short*)hf16, (const unsigned short*)hb16,
                                    bio, bioE, emiW, emib, (unsigned short*)oc16, emi);

  // u = relu(oc@suW^T+sub), v = relu(oc@svW^T+svb)
  k_bgemm<true, true><<<dim3(2, 32, 2), 256, 0, stream>>>(
      (const unsigned short*)oc16, (const uint4*)suPk, sub, (unsigned short*)u16,
      (const unsigned short*)oc16, (const uint4*)svPk, svb, (unsigned short*)v16,
      2048, 128, 320);

  // a = u@W1^T, c = v@W2^T
  k_bgemm<false, false><<<dim3(2, 32, 2), 256, 0, stream>>>(
      (const unsigned short*)u16, (const uint4*)w1Pk, nullptr, (unsigned short*)a16,
      (const unsigned short*)v16, (const uint4*)w2Pk, nullptr, (unsigned short*)c16,
      2048, 128, 128);

  k_loss<<<1040, 256, 0, stream>>>((const unsigned short*)a16, (const unsigned short*)c16,
                                   suvb, rel, selg, tokens, emi, bio,
                                   cstart, cend, ctrans, acc, (float*)d_out);
}